// Round 3
// baseline (449.041 us; speedup 1.0000x reference)
//
#include <hip/hip_runtime.h>

typedef __attribute__((ext_vector_type(4))) float f32x4;
typedef __attribute__((ext_vector_type(8))) short bf16x8;
typedef __attribute__((ext_vector_type(4))) unsigned short u16x4;
typedef unsigned short u16;

#define HW 3136
#define NSEG 49
#define NELF 802816.0f
#define EPS 1e-5f

__device__ __forceinline__ short f2bf(float f) {
  union { float f; unsigned u; } v; v.f = f;
  unsigned r = (v.u + 0x7FFFu + ((v.u >> 16) & 1u)) >> 16;
  return (short)r;
}
__device__ __forceinline__ float b2f(u16 u) {
  union { unsigned u; float f; } v; v.u = ((unsigned)u) << 16;
  return v.f;
}
__device__ __forceinline__ float fgelu(float x) {
  // tanh-form gelu via hw exp: 0.5x(1+tanh(u)) = x * sigmoid(2u)
  float x2 = x * x;
  float u = x * (0.7978845608f + 0.0356774081f * x2);
  float e = __expf(-2.0f * u);
  return x * __builtin_amdgcn_rcpf(1.0f + e);
}

// ---- W0a: fold GN column scales into weights, convert to bf16 ----
__global__ void wfold_kernel(const float* __restrict__ c1, const float* __restrict__ c21,
                             const float* __restrict__ c22, const float* __restrict__ c3,
                             const float* __restrict__ fc1, const float* __restrict__ fc2,
                             const float* __restrict__ n1w, const float* __restrict__ an2w,
                             const float* __restrict__ n2w, u16* __restrict__ out) {
  int i = (blockIdx.x * 256 + threadIdx.x) * 4;
  const float* src; int off; const float* scale = nullptr;
  if (i < 65536)       { src = c1;  off = 0;       scale = n1w; }
  else if (i < 131072) { src = c21; off = 65536; }
  else if (i < 196608) { src = c22; off = 131072; }
  else if (i < 262144) { src = c3;  off = 196608;  scale = an2w; }
  else if (i < 524288) { src = fc1; off = 262144;  scale = n2w; }
  else                 { src = fc2; off = 524288; }
  int li = i - off;
  float4 v = *(const float4*)(src + li);
  if (scale) {
    float4 g = *(const float4*)(scale + (li & 255));
    v.x *= g.x; v.y *= g.y; v.z *= g.z; v.w *= g.w;
  }
  u16x4 o4; o4[0] = (u16)f2bf(v.x); o4[1] = (u16)f2bf(v.y); o4[2] = (u16)f2bf(v.z); o4[3] = (u16)f2bf(v.w);
  *(u16x4*)(out + i) = o4;
}

// ---- W0b: row sums Sg[o] = sum_c W[o][c]*gw[c]; Sb[o] = conv_b[o] + sum_c W[o][c]*gb[c] ----
__global__ void rowsum_kernel(const float* __restrict__ c1w, const float* __restrict__ c1b,
                              const float* __restrict__ n1w, const float* __restrict__ n1b,
                              const float* __restrict__ c3w, const float* __restrict__ c3b,
                              const float* __restrict__ an2w, const float* __restrict__ an2b,
                              const float* __restrict__ fc1w, const float* __restrict__ fc1b,
                              const float* __restrict__ n2w, const float* __restrict__ n2b,
                              float* __restrict__ sums) {
  int o = blockIdx.x * 256 + threadIdx.x;  // 0..1535
  const float *W, *gw, *gb, *cb; float *Sg, *Sb; int row;
  if (o < 256)      { W = c1w;  gw = n1w;  gb = n1b;  cb = c1b;  Sg = sums;        Sb = sums + 256;  row = o; }
  else if (o < 512) { W = c3w;  gw = an2w; gb = an2b; cb = c3b;  Sg = sums + 512;  Sb = sums + 768;  row = o - 256; }
  else              { W = fc1w; gw = n2w;  gb = n2b;  cb = fc1b; Sg = sums + 1024; Sb = sums + 2048; row = o - 512; }
  float sg = 0.f, sb = 0.f;
  for (int c = 0; c < 256; c += 4) {
    float4 w = *(const float4*)(W + (size_t)row * 256 + c);
    float4 g = *(const float4*)(gw + c);
    float4 b = *(const float4*)(gb + c);
    sg += w.x * g.x + w.y * g.y + w.z * g.z + w.w * g.w;
    sb += w.x * b.x + w.y * b.y + w.z * b.z + w.w * b.w;
  }
  Sg[row] = sg; Sb[row] = sb + cb[row];
}

// ---- T0: stats(x) + transpose x -> xT bf16 [n][pix][c] ----
__global__ __launch_bounds__(256) void t0_kernel(const float* __restrict__ x,
                                                 u16* __restrict__ xT, float* __restrict__ st) {
  __shared__ __align__(16) u16 tile[64 * 256];
  const int t = threadIdx.x;
  const int n = blockIdx.x / NSEG;
  const int hw0 = (blockIdx.x % NSEG) * 64;
  const int pix = t & 63;
  float s = 0.f, q = 0.f;
#pragma unroll
  for (int r = 0; r < 16; ++r) {
    int cq = (t >> 6) + (r << 2);
    int c = cq * 4;
    u16x4 o4;
#pragma unroll
    for (int i = 0; i < 4; ++i) {
      float v = x[((size_t)n * 256 + c + i) * HW + hw0 + pix];
      s += v; q += v * v;
      o4[i] = (u16)f2bf(v);
    }
    int u = cq ^ ((pix & 15) << 2);
    *(u16x4*)((char*)tile + pix * 512 + u * 8) = o4;
  }
  __syncthreads();
  {
    const int p2 = t >> 2;
#pragma unroll
    for (int r = 0; r < 8; ++r) {
      int oct = (t & 3) + (r << 2);
      int up = (2 * oct) ^ ((p2 & 15) << 2);
      bf16x8 v = *(const bf16x8*)((char*)tile + p2 * 512 + up * 8);
      *(bf16x8*)&xT[((size_t)n * HW + hw0 + p2) * 256 + oct * 8] = v;
    }
  }
  __syncthreads();
  float* red = (float*)tile;
  red[t] = s; red[256 + t] = q;
  __syncthreads();
  for (int off = 128; off > 0; off >>= 1) {
    if (t < off) { red[t] += red[t + off]; red[256 + t] += red[256 + t + off]; }
    __syncthreads();
  }
  if (t == 0) { atomicAdd(&st[n * 2], red[0]); atomicAdd(&st[n * 2 + 1], red[256]); }
}

// ---- E2: t = fgelu(gn_as1(y)) elementwise, [c][pix] bf16 ----
__global__ void e2_kernel(const u16* __restrict__ y, u16* __restrict__ tb,
                          const float* __restrict__ gw, const float* __restrict__ gb,
                          const float* __restrict__ stats) {
  const size_t NG = (size_t)16 * 256 * 392;
  for (size_t g = (size_t)blockIdx.x * blockDim.x + threadIdx.x; g < NG;
       g += (size_t)gridDim.x * blockDim.x) {
    size_t base = g * 8;
    int n = (int)(base / 802816);
    int c = (int)((base / HW) & 255);
    float sm = stats[n * 2], sq = stats[n * 2 + 1];
    float mn = sm * (1.0f / NELF);
    float rstd = rsqrtf(sq * (1.0f / NELF) - mn * mn + EPS);
    float scale = rstd * gw[c];
    float shift = gb[c] - mn * scale;
    bf16x8 v = *(const bf16x8*)(y + base);
    bf16x8 o;
#pragma unroll
    for (int j = 0; j < 8; ++j) o[j] = f2bf(fgelu(b2f((u16)v[j]) * scale + shift));
    *(bf16x8*)(tb + base) = o;
  }
}

// ---- main LDS-free GEMM (activations channel-last) ----
// EPI: 0 = y (fold-scale, store [c][pix] bf16 via LDS transpose, stats)
//      1 = x2 (fold-scale, +resid f32, store [pix][c] bf16, stats)
//      2 = hid (fold-scale, fgelu, store [pix][c] bf16)
//      3 = out (plain bias, +resid bf16[pix][c], store f32 [c][pix])
template<int KTOT, int OTOT, int EPI>
__global__ __launch_bounds__(256, 2) void gemmT(
    const u16* __restrict__ actT, const u16* __restrict__ wt,
    const float* __restrict__ Sg, const float* __restrict__ Sbc,
    const float* __restrict__ stats_in, float* __restrict__ stats_out,
    const float* __restrict__ resid_f32, const u16* __restrict__ resid_bf,
    const float* __restrict__ bias, float* __restrict__ out_f32,
    u16* __restrict__ y_cp, u16* __restrict__ outT)
{
  __shared__ __align__(16) u16 tile[256 * 72];   // 36 KB
  const int t = threadIdx.x;
  const int lane = t & 63, wave = t >> 6;
  const int fr = lane & 15, fq = lane >> 4;
  const int n = blockIdx.x / NSEG;
  const int hw0 = (blockIdx.x % NSEG) * 64;
  const int obase = blockIdx.y * 256 + wave * 64;

  float mr = 0.f, rstd = 0.f;
  if (EPI != 3) {
    float sm = stats_in[n * 2], sq = stats_in[n * 2 + 1];
    float mn = sm * (1.0f / NELF);
    rstd = rsqrtf(sq * (1.0f / NELF) - mn * mn + EPS);
    mr = mn * rstd;
  }

  f32x4 acc[4][4];
#pragma unroll
  for (int a = 0; a < 4; ++a)
#pragma unroll
    for (int b = 0; b < 4; ++b) acc[a][b] = (f32x4){0.f, 0.f, 0.f, 0.f};

  const u16* bp[4];
  const u16* ap[4];
#pragma unroll
  for (int ps = 0; ps < 4; ++ps)
    bp[ps] = actT + ((size_t)n * HW + hw0 + ps * 16 + fr) * KTOT + fq * 8;
#pragma unroll
  for (int os = 0; os < 4; ++os)
    ap[os] = wt + (size_t)(obase + os * 16 + fr) * KTOT + fq * 8;

  for (int k0 = 0; k0 < KTOT; k0 += 32) {
    bf16x8 bfr[4], afr[4];
#pragma unroll
    for (int ps = 0; ps < 4; ++ps) bfr[ps] = *(const bf16x8*)(bp[ps] + k0);
#pragma unroll
    for (int os = 0; os < 4; ++os) afr[os] = *(const bf16x8*)(ap[os] + k0);
#pragma unroll
    for (int os = 0; os < 4; ++os)
#pragma unroll
      for (int ps = 0; ps < 4; ++ps)
        acc[os][ps] = __builtin_amdgcn_mfma_f32_16x16x32_bf16(afr[os], bfr[ps], acc[os][ps], 0, 0, 0);
  }

  float lsum = 0.f, lsq = 0.f;

  if (EPI == 0) {
#pragma unroll
    for (int os = 0; os < 4; ++os) {
      int ob = obase + os * 16 + fq * 4;
      float4 sg = *(const float4*)&Sg[ob];
      float4 sb = *(const float4*)&Sbc[ob];
      float be[4] = {sb.x - mr * sg.x, sb.y - mr * sg.y, sb.z - mr * sg.z, sb.w - mr * sg.w};
#pragma unroll
      for (int ps = 0; ps < 4; ++ps) {
        int pix = ps * 16 + fr;
#pragma unroll
        for (int j = 0; j < 4; ++j) {
          float v = fmaf(acc[os][ps][j], rstd, be[j]);
          lsum += v; lsq += v * v;
          int ol = wave * 64 + os * 16 + fq * 4 + j;
          tile[ol * 72 + (((pix >> 3) ^ (ol & 7)) << 3) + (pix & 7)] = (u16)f2bf(v);
        }
      }
    }
    __syncthreads();
#pragma unroll
    for (int r = 0; r < 8; ++r) {
      int ol = (t >> 3) + (r << 5);
      int s8 = (t & 7) ^ (ol & 7);
      bf16x8 v = *(const bf16x8*)&tile[ol * 72 + s8 * 8];
      *(bf16x8*)&y_cp[((size_t)n * 256 + ol) * HW + hw0 + (t & 7) * 8] = v;
    }
  } else if (EPI == 1 || EPI == 2) {
#pragma unroll
    for (int os = 0; os < 4; ++os) {
      int ob = obase + os * 16 + fq * 4;
      float4 sg = *(const float4*)&Sg[ob];
      float4 sb = *(const float4*)&Sbc[ob];
      float be[4] = {sb.x - mr * sg.x, sb.y - mr * sg.y, sb.z - mr * sg.z, sb.w - mr * sg.w};
#pragma unroll
      for (int ps = 0; ps < 4; ++ps) {
        int pix = ps * 16 + fr;
        u16x4 pk;
#pragma unroll
        for (int j = 0; j < 4; ++j) {
          float v = fmaf(acc[os][ps][j], rstd, be[j]);
          if (EPI == 1) {
            v += resid_f32[((size_t)n * 256 + ob + j) * HW + hw0 + pix];
            lsum += v; lsq += v * v;
          } else {
            v = fgelu(v);
          }
          pk[j] = (u16)f2bf(v);
        }
        int qd = wave * 16 + os * 4 + fq;
        int uq = qd ^ ((pix & 15) << 2);
        *(u16x4*)((char*)tile + pix * 512 + uq * 8) = pk;
      }
    }
    __syncthreads();
    {
      int p2 = t >> 2;
#pragma unroll
      for (int r = 0; r < 8; ++r) {
        int oct = (t & 3) + (r << 2);
        int up = (2 * oct) ^ ((p2 & 15) << 2);
        bf16x8 v = *(const bf16x8*)((char*)tile + p2 * 512 + up * 8);
        *(bf16x8*)&outT[((size_t)n * HW + hw0 + p2) * OTOT + blockIdx.y * 256 + oct * 8] = v;
      }
    }
  } else {
#pragma unroll
    for (int os = 0; os < 4; ++os) {
      int ob = obase + os * 16 + fq * 4;
      float4 b4 = *(const float4*)&bias[ob];
      float bb[4] = {b4.x, b4.y, b4.z, b4.w};
#pragma unroll
      for (int ps = 0; ps < 4; ++ps) {
        int pix = ps * 16 + fr;
        size_t rbase = ((size_t)n * HW + hw0 + pix) * 256 + ob;
#pragma unroll
        for (int j = 0; j < 4; ++j) {
          float v = acc[os][ps][j] + bb[j] + b2f(resid_bf[rbase + j]);
          out_f32[((size_t)n * 256 + ob + j) * HW + hw0 + pix] = v;
        }
      }
    }
  }

  if (EPI == 0 || EPI == 1) {
    __syncthreads();
    float* red = (float*)tile;
    red[t] = lsum; red[256 + t] = lsq;
    __syncthreads();
    for (int off = 128; off > 0; off >>= 1) {
      if (t < off) { red[t] += red[t + off]; red[256 + t] += red[256 + t + off]; }
      __syncthreads();
    }
    if (t == 0) { atomicAdd(&stats_out[n * 2], red[0]); atomicAdd(&stats_out[n * 2 + 1], red[256]); }
  }
}

// ---- G2: dual shifted GEMM, one-shot LDS staging, z -> [pix][c] bf16 ----
__global__ __launch_bounds__(256, 2) void gemm_dual2(
    const u16* __restrict__ tact, const u16* __restrict__ wA, const u16* __restrict__ wB,
    const float* __restrict__ biasA, const float* __restrict__ biasB,
    float* __restrict__ stats_out, u16* __restrict__ zT)
{
  __shared__ __align__(16) u16 tA[64 * 256];
  __shared__ __align__(16) u16 tB[64 * 256];
  const int t = threadIdx.x;
  const int lane = t & 63, wave = t >> 6;
  const int fr = lane & 15, fq = lane >> 4;
  const int n = blockIdx.x / NSEG;
  const int hw0 = (blockIdx.x % NSEG) * 64;
  const int pix = t & 63;
  const int hw = hw0 + pix;
  const int shp = hw / 56, swp = hw % 56;
  const size_t nb = (size_t)n * 256;

#pragma unroll
  for (int r = 0; r < 8; ++r) {
    int oct = (t >> 6) + (r << 2);
    bf16x8 sA, sB;
#pragma unroll
    for (int j = 0; j < 8; ++j) {
      int c = oct * 8 + j;
      int s = 3 - c / 37;
      const u16* row = tact + (nb + c) * HW;
      int fa = hw + s; fa = fa < 0 ? 0 : (fa > HW - 1 ? HW - 1 : fa);
      sA[j] = ((unsigned)(swp + s) < 56u) ? (short)row[fa] : (short)0;
      int fb = hw + 56 * s; fb = fb < 0 ? 0 : (fb > HW - 1 ? HW - 1 : fb);
      sB[j] = ((unsigned)(shp + s) < 56u) ? (short)row[fb] : (short)0;
    }
    int up = (2 * oct) ^ ((pix & 15) << 2);
    *(bf16x8*)((char*)tA + pix * 512 + up * 8) = sA;
    *(bf16x8*)((char*)tB + pix * 512 + up * 8) = sB;
  }
  __syncthreads();

  f32x4 accA[4][4], accB[4][4];
#pragma unroll
  for (int a = 0; a < 4; ++a)
#pragma unroll
    for (int b = 0; b < 4; ++b) { accA[a][b] = (f32x4){0,0,0,0}; accB[a][b] = (f32x4){0,0,0,0}; }

#pragma unroll
  for (int ko = 0; ko < 8; ++ko) {
    bf16x8 bfrA[4], bfrB[4];
#pragma unroll
    for (int ps = 0; ps < 4; ++ps) {
      int row = ps * 16 + fr;
      int oc = ko * 4 + fq;
      int up = (2 * oc) ^ ((row & 15) << 2);
      bfrA[ps] = *(const bf16x8*)((char*)tA + row * 512 + up * 8);
      bfrB[ps] = *(const bf16x8*)((char*)tB + row * 512 + up * 8);
    }
#pragma unroll
    for (int os = 0; os < 4; ++os) {
      bf16x8 afrA = *(const bf16x8*)&wA[(size_t)(wave * 64 + os * 16 + fr) * 256 + ko * 32 + fq * 8];
      bf16x8 afrB = *(const bf16x8*)&wB[(size_t)(wave * 64 + os * 16 + fr) * 256 + ko * 32 + fq * 8];
#pragma unroll
      for (int ps = 0; ps < 4; ++ps) {
        accA[os][ps] = __builtin_amdgcn_mfma_f32_16x16x32_bf16(afrA, bfrA[ps], accA[os][ps], 0, 0, 0);
        accB[os][ps] = __builtin_amdgcn_mfma_f32_16x16x32_bf16(afrB, bfrB[ps], accB[os][ps], 0, 0, 0);
      }
    }
  }

  __syncthreads();  // frag reads done; reuse tA for transposed store
  float lsum = 0.f, lsq = 0.f;
#pragma unroll
  for (int os = 0; os < 4; ++os) {
    int ob = wave * 64 + os * 16 + fq * 4;
    float4 a4 = *(const float4*)&biasA[ob];
    float4 b4 = *(const float4*)&biasB[ob];
    float ba[4] = {a4.x, a4.y, a4.z, a4.w};
    float bb[4] = {b4.x, b4.y, b4.z, b4.w};
#pragma unroll
    for (int ps = 0; ps < 4; ++ps) {
      int px = ps * 16 + fr;
      u16x4 pk;
#pragma unroll
      for (int j = 0; j < 4; ++j) {
        float z = fgelu(accA[os][ps][j] + ba[j]) + fgelu(accB[os][ps][j] + bb[j]);
        lsum += z; lsq += z * z;
        pk[j] = (u16)f2bf(z);
      }
      int qd = wave * 16 + os * 4 + fq;
      int uq = qd ^ ((px & 15) << 2);
      *(u16x4*)((char*)tA + px * 512 + uq * 8) = pk;
    }
  }
  __syncthreads();
  {
    int p2 = t >> 2;
#pragma unroll
    for (int r = 0; r < 8; ++r) {
      int oct = (t & 3) + (r << 2);
      int up = (2 * oct) ^ ((p2 & 15) << 2);
      bf16x8 v = *(const bf16x8*)((char*)tA + p2 * 512 + up * 8);
      *(bf16x8*)&zT[((size_t)n * HW + hw0 + p2) * 256 + oct * 8] = v;
    }
  }
  __syncthreads();
  float* red = (float*)tA;
  red[t] = lsum; red[256 + t] = lsq;
  __syncthreads();
  for (int off = 128; off > 0; off >>= 1) {
    if (t < off) { red[t] += red[t + off]; red[256 + t] += red[256 + t + off]; }
    __syncthreads();
  }
  if (t == 0) { atomicAdd(&stats_out[n * 2], red[0]); atomicAdd(&stats_out[n * 2 + 1], red[256]); }
}

extern "C" void kernel_launch(void* const* d_in, const int* in_sizes, int n_in,
                              void* d_out, int out_size, void* d_ws, size_t ws_size,
                              hipStream_t stream) {
  const float* x     = (const float*)d_in[0];
  const float* n1_w  = (const float*)d_in[1];
  const float* n1_b  = (const float*)d_in[2];
  const float* c1_w  = (const float*)d_in[3];
  const float* c1_b  = (const float*)d_in[4];
  const float* an1_w = (const float*)d_in[5];
  const float* an1_b = (const float*)d_in[6];
  const float* c21_w = (const float*)d_in[7];
  const float* c21_b = (const float*)d_in[8];
  const float* c22_w = (const float*)d_in[9];
  const float* c22_b = (const float*)d_in[10];
  const float* an2_w = (const float*)d_in[11];
  const float* an2_b = (const float*)d_in[12];
  const float* c3_w  = (const float*)d_in[13];
  const float* c3_b  = (const float*)d_in[14];
  const float* n2_w  = (const float*)d_in[15];
  const float* n2_b  = (const float*)d_in[16];
  const float* fc1_w = (const float*)d_in[17];
  const float* fc1_b = (const float*)d_in[18];
  const float* fc2_w = (const float*)d_in[19];
  const float* fc2_b = (const float*)d_in[20];

  char* ws = (char*)d_ws;
  float* stats = (float*)ws;                    // 512 B
  float* sums  = (float*)(ws + 1024);           // Sg1,Sb1,Sg3,Sb3 (256 each), Sgf,Sbf (1024 each)
  u16* wbuf = (u16*)(ws + 16384);               // 1.57 MB folded bf16 weights
  u16* wb_c1g  = wbuf;
  u16* wb_c21  = wbuf + 65536;
  u16* wb_c22  = wbuf + 131072;
  u16* wb_c3g  = wbuf + 196608;
  u16* wb_fc1g = wbuf + 262144;
  u16* wb_fc2  = wbuf + 524288;
  const size_t AB = 25690112;                   // bytes per bf16 activation tensor
  char* SB = ws + 1638400;
  u16* xT  = (u16*)(SB);
  u16* yb  = (u16*)(SB + AB);
  u16* tb  = (u16*)(SB + 2 * AB);
  u16* zT  = (u16*)(SB + 3 * AB);
  u16* x2T = (u16*)(SB + 4 * AB);
  u16* hidT = (u16*)(SB);                       // 102.76 MB, overlays xT..zT (dead by G4)
  float* out = (float*)d_out;

  hipMemsetAsync(stats, 0, 512, stream);
  wfold_kernel<<<768, 256, 0, stream>>>(c1_w, c21_w, c22_w, c3_w, fc1_w, fc2_w,
                                        n1_w, an2_w, n2_w, wbuf);
  rowsum_kernel<<<6, 256, 0, stream>>>(c1_w, c1_b, n1_w, n1_b, c3_w, c3_b, an2_w, an2_b,
                                       fc1_w, fc1_b, n2_w, n2_b, sums);
  t0_kernel<<<784, 256, 0, stream>>>(x, xT, stats + 0);
  // G1: y = conv1(gn1(x)) -> y [c][pix] bf16, stats(y)
  gemmT<256, 256, 0><<<dim3(784, 1), 256, 0, stream>>>(
      xT, wb_c1g, sums, sums + 256, stats + 0, stats + 32, nullptr, nullptr, nullptr,
      nullptr, yb, nullptr);
  // E2: t = fgelu(gn_as1(y))
  e2_kernel<<<2048, 256, 0, stream>>>(yb, tb, an1_w, an1_b, stats + 32);
  // G2: z = fgelu(conv21(shift_w t)) + fgelu(conv22(shift_h t)) -> zT, stats(z)
  gemm_dual2<<<784, 256, 0, stream>>>(tb, wb_c21, wb_c22, c21_b, c22_b, stats + 64, zT);
  // G3: x2 = x + conv3(gn_as2(z)) -> x2T bf16, stats(x2)
  gemmT<256, 256, 1><<<dim3(784, 1), 256, 0, stream>>>(
      zT, wb_c3g, sums + 512, sums + 768, stats + 64, stats + 96, x, nullptr, nullptr,
      nullptr, nullptr, x2T);
  // G4: hid = fgelu(fc1(gn2(x2))) -> hidT bf16
  gemmT<256, 1024, 2><<<dim3(784, 4), 256, 0, stream>>>(
      x2T, wb_fc1g, sums + 1024, sums + 2048, stats + 96, nullptr, nullptr, nullptr,
      nullptr, nullptr, nullptr, hidT);
  // G5: out = x2 + fc2(hid) -> d_out f32
  gemmT<1024, 256, 3><<<dim3(784, 1), 256, 0, stream>>>(
      hidT, wb_fc2, nullptr, nullptr, nullptr, nullptr, nullptr, x2T, fc2_b,
      out, nullptr, nullptr);
}

// Round 4
// 317.115 us; speedup vs baseline: 1.4160x; 1.4160x over previous
//
#include <hip/hip_runtime.h>

typedef __attribute__((ext_vector_type(4))) float f32x4;
typedef __attribute__((ext_vector_type(8))) short bf16x8;
typedef __attribute__((ext_vector_type(4))) unsigned short u16x4;
typedef unsigned short u16;

#define HW 3136
#define NSEG 49
#define NELF 802816.0f
#define EPS 1e-5f

__device__ __forceinline__ short f2bf(float f) {
  union { float f; unsigned u; } v; v.f = f;
  unsigned r = (v.u + 0x7FFFu + ((v.u >> 16) & 1u)) >> 16;
  return (short)r;
}
__device__ __forceinline__ float b2f(u16 u) {
  union { unsigned u; float f; } v; v.u = ((unsigned)u) << 16;
  return v.f;
}
__device__ __forceinline__ float fgelu(float x) {
  float x2 = x * x;
  float u = x * (0.7978845608f + 0.0356774081f * x2);
  float e = __expf(-2.0f * u);
  return x * __builtin_amdgcn_rcpf(1.0f + e);
}
// CK-style global->LDS direct copy: lane writes lds_base + lane*16
__device__ __forceinline__ void gload16(const void* g, void* l) {
  __builtin_amdgcn_global_load_lds(
      (const __attribute__((address_space(1))) void*)(uintptr_t)g,
      (__attribute__((address_space(3))) void*)(unsigned)(uintptr_t)l,
      16, 0, 0);
}

// ---- W0a: fold GN column scales into weights, convert to bf16 ----
__global__ void wfold_kernel(const float* __restrict__ c1, const float* __restrict__ c21,
                             const float* __restrict__ c22, const float* __restrict__ c3,
                             const float* __restrict__ fc1, const float* __restrict__ fc2,
                             const float* __restrict__ n1w, const float* __restrict__ an2w,
                             const float* __restrict__ n2w, u16* __restrict__ out) {
  int i = (blockIdx.x * 256 + threadIdx.x) * 4;
  const float* src; int off; const float* scale = nullptr;
  if (i < 65536)       { src = c1;  off = 0;       scale = n1w; }
  else if (i < 131072) { src = c21; off = 65536; }
  else if (i < 196608) { src = c22; off = 131072; }
  else if (i < 262144) { src = c3;  off = 196608;  scale = an2w; }
  else if (i < 524288) { src = fc1; off = 262144;  scale = n2w; }
  else                 { src = fc2; off = 524288; }
  int li = i - off;
  float4 v = *(const float4*)(src + li);
  if (scale) {
    float4 g = *(const float4*)(scale + (li & 255));
    v.x *= g.x; v.y *= g.y; v.z *= g.z; v.w *= g.w;
  }
  u16x4 o4; o4[0] = (u16)f2bf(v.x); o4[1] = (u16)f2bf(v.y); o4[2] = (u16)f2bf(v.z); o4[3] = (u16)f2bf(v.w);
  *(u16x4*)(out + i) = o4;
}

// ---- W0b: Sg[o]=sum_c W[o][c]*gw[c]; Sb[o]=conv_b[o]+sum_c W[o][c]*gb[c] ----
__global__ void rowsum_kernel(const float* __restrict__ c1w, const float* __restrict__ c1b,
                              const float* __restrict__ n1w, const float* __restrict__ n1b,
                              const float* __restrict__ c3w, const float* __restrict__ c3b,
                              const float* __restrict__ an2w, const float* __restrict__ an2b,
                              const float* __restrict__ fc1w, const float* __restrict__ fc1b,
                              const float* __restrict__ n2w, const float* __restrict__ n2b,
                              float* __restrict__ sums) {
  int o = blockIdx.x * 256 + threadIdx.x;  // 0..1535
  const float *W, *gw, *gb, *cb; float *Sg, *Sb; int row;
  if (o < 256)      { W = c1w;  gw = n1w;  gb = n1b;  cb = c1b;  Sg = sums;        Sb = sums + 256;  row = o; }
  else if (o < 512) { W = c3w;  gw = an2w; gb = an2b; cb = c3b;  Sg = sums + 512;  Sb = sums + 768;  row = o - 256; }
  else              { W = fc1w; gw = n2w;  gb = n2b;  cb = fc1b; Sg = sums + 1024; Sb = sums + 2048; row = o - 512; }
  float sg = 0.f, sb = 0.f;
  for (int c = 0; c < 256; c += 4) {
    float4 w = *(const float4*)(W + (size_t)row * 256 + c);
    float4 g = *(const float4*)(gw + c);
    float4 b = *(const float4*)(gb + c);
    sg += w.x * g.x + w.y * g.y + w.z * g.z + w.w * g.w;
    sb += w.x * b.x + w.y * b.y + w.z * b.z + w.w * b.w;
  }
  Sg[row] = sg; Sb[row] = sb + cb[row];
}

// ---- T0: stats(x) + transpose x -> xT bf16 [n][pix][c] ----
__global__ __launch_bounds__(256) void t0_kernel(const float* __restrict__ x,
                                                 u16* __restrict__ xT, float* __restrict__ st) {
  __shared__ __align__(16) u16 tile[64 * 256];
  const int t = threadIdx.x;
  const int n = blockIdx.x / NSEG;
  const int hw0 = (blockIdx.x % NSEG) * 64;
  const int pix = t & 63;
  float s = 0.f, q = 0.f;
#pragma unroll
  for (int r = 0; r < 16; ++r) {
    int cq = (t >> 6) + (r << 2);
    int c = cq * 4;
    u16x4 o4;
#pragma unroll
    for (int i = 0; i < 4; ++i) {
      float v = x[((size_t)n * 256 + c + i) * HW + hw0 + pix];
      s += v; q += v * v;
      o4[i] = (u16)f2bf(v);
    }
    int u = cq ^ ((pix & 15) << 2);
    *(u16x4*)((char*)tile + pix * 512 + u * 8) = o4;
  }
  __syncthreads();
  {
    const int p2 = t >> 2;
#pragma unroll
    for (int r = 0; r < 8; ++r) {
      int oct = (t & 3) + (r << 2);
      int up = (2 * oct) ^ ((p2 & 15) << 2);
      bf16x8 v = *(const bf16x8*)((char*)tile + p2 * 512 + up * 8);
      *(bf16x8*)&xT[((size_t)n * HW + hw0 + p2) * 256 + oct * 8] = v;
    }
  }
  __syncthreads();
  float* red = (float*)tile;
  red[t] = s; red[256 + t] = q;
  __syncthreads();
  for (int off = 128; off > 0; off >>= 1) {
    if (t < off) { red[t] += red[t + off]; red[256 + t] += red[256 + t + off]; }
    __syncthreads();
  }
  if (t == 0) { atomicAdd(&st[n * 2], red[0]); atomicAdd(&st[n * 2 + 1], red[256]); }
}

// ---- E2: t = fgelu(gn_as1(y)), channel-last elementwise ----
__global__ void e2_kernel(const u16* __restrict__ y, u16* __restrict__ tb,
                          const float* __restrict__ gw, const float* __restrict__ gb,
                          const float* __restrict__ stats) {
  const size_t NG = (size_t)16 * HW * 32;
  for (size_t g = (size_t)blockIdx.x * blockDim.x + threadIdx.x; g < NG;
       g += (size_t)gridDim.x * blockDim.x) {
    size_t base = g * 8;
    int n = (int)(base / 802816);
    int c0 = (int)(base & 255);
    float sm = stats[n * 2], sq = stats[n * 2 + 1];
    float mn = sm * (1.0f / NELF);
    float rstd = rsqrtf(sq * (1.0f / NELF) - mn * mn + EPS);
    bf16x8 v = *(const bf16x8*)(y + base);
    bf16x8 o;
#pragma unroll
    for (int j = 0; j < 8; ++j) {
      float sc = rstd * gw[c0 + j];
      float sh = gb[c0 + j] - mn * sc;
      o[j] = f2bf(fgelu(b2f((u16)v[j]) * sc + sh));
    }
    *(bf16x8*)(tb + base) = o;
  }
}

// ---- main m97-style GEMM: A(weights 256x32) + B(act 64x32) staged in LDS, dbuf ----
// sigma-swizzle: unit u=(row,j) holds k-seg ((j - (row>>1)) & 3); reader U=4*row+((fq+(row>>1))&3)
// PRO: 0 none; 1 shift_w fold; 2 shift_h fold (src-addr shift + fixup writes)
// EPI: 0 y: fold, store CL + stats | 1 x2: fold + residCL + store CL + stats
//      2 hid: fold + gelu + store CL | 3 out: bias + residCL + f32 [c][pix] store
//      4 zA: bias + gelu + store CL | 5 zT: bias + gelu + residCL-add + store CL + stats
#define STG(bsel, ks_) do {                                                              \
    const int k0_ = (ks_) * 32;                                                          \
    if (PRO == 0) {                                                                      \
      gload16(srcB0 + k0_, &lds[16384 + (bsel) * 2048 + wave * 512]);                    \
    } else {                                                                             \
      int c0_ = k0_ + segB * 8;                                                          \
      int g0_ = c0_ / 37;                                                                \
      int js_ = (g0_ + 1) * 37 - c0_;                                                    \
      int s0_ = 3 - g0_;                                                                 \
      if (js_ >= 8) {                                                                    \
        if ((unsigned)(wpB + s0_) < 56u) {                                               \
          int dp_ = (PRO == 1) ? s0_ : 56 * s0_;                                         \
          gload16(actT + (nHW + pB + dp_) * KTOT + segB * 8 + k0_,                       \
                  &lds[16384 + (bsel) * 2048 + wave * 512]);                             \
        } else {                                                                         \
          bf16x8 zz = {0, 0, 0, 0, 0, 0, 0, 0};                                          \
          *(bf16x8*)&lds[16384 + (bsel) * 2048 + t * 8] = zz;                            \
        }                                                                                \
      } else {                                                                           \
        bf16x8 vv;                                                                       \
        _Pragma("unroll") for (int j = 0; j < 8; ++j) {                                  \
          int s_ = s0_ - (j >= js_ ? 1 : 0);                                             \
          int dp_ = (PRO == 1) ? s_ : 56 * s_;                                           \
          int pp_ = pB + dp_; pp_ = pp_ < 0 ? 0 : (pp_ > HW - 1 ? HW - 1 : pp_);         \
          u16 uv = actT[(nHW + pp_) * KTOT + c0_ + j];                                   \
          vv[j] = ((unsigned)(wpB + s_) < 56u) ? (short)uv : (short)0;                   \
        }                                                                                \
        *(bf16x8*)&lds[16384 + (bsel) * 2048 + t * 8] = vv;                              \
      }                                                                                  \
    }                                                                                    \
    gload16(sA0 + k0_, &lds[(bsel) * 8192 + wave * 512]);                                \
    gload16(sA1 + k0_, &lds[(bsel) * 8192 + 2048 + wave * 512]);                         \
    gload16(sA2 + k0_, &lds[(bsel) * 8192 + 4096 + wave * 512]);                         \
    gload16(sA3 + k0_, &lds[(bsel) * 8192 + 6144 + wave * 512]);                         \
  } while (0)

template<int KTOT, int OTOT, int PRO, int EPI>
__global__ __launch_bounds__(256, 3) void gemmS(
    const u16* __restrict__ actT, const u16* __restrict__ wt,
    const float* __restrict__ Sg, const float* __restrict__ Sb,
    const float* __restrict__ stats_in, float* __restrict__ stats_out,
    const u16* __restrict__ residCL, float* __restrict__ out_f32,
    u16* __restrict__ outT)
{
  constexpr int NK = KTOT / 32;
  constexpr bool FOLD = (EPI == 0 || EPI == 1 || EPI == 2);
  __shared__ __align__(16) u16 lds[20480];   // A0[8192] A1[8192] B0[2048] B1[2048]
  const int t = threadIdx.x;
  const int lane = t & 63, wave = t >> 6;
  const int fr = lane & 15, fq = lane >> 4;
  const int n = blockIdx.x / NSEG;
  const int hw0 = (blockIdx.x % NSEG) * 64;
  const int obase_blk = blockIdx.y * 256;
  const size_t nHW = (size_t)n * HW;

  // staging precompute (B unit = t; A units = t + 256*i)
  const int rB = t >> 2;
  const int segB = ((t & 3) - (rB >> 1)) & 3;
  const int pB = hw0 + rB;
  int wpB = 0;
  if (PRO == 1) wpB = pB % 56;
  if (PRO == 2) wpB = pB / 56;
  const u16* srcB0 = actT + (nHW + pB) * KTOT + segB * 8;
  const u16 *sA0, *sA1, *sA2, *sA3;
  {
    int u, r, sg;
    u = t;       r = u >> 2; sg = ((u & 3) - (r >> 1)) & 3; sA0 = wt + (size_t)(obase_blk + r) * KTOT + sg * 8;
    u = t + 256; r = u >> 2; sg = ((u & 3) - (r >> 1)) & 3; sA1 = wt + (size_t)(obase_blk + r) * KTOT + sg * 8;
    u = t + 512; r = u >> 2; sg = ((u & 3) - (r >> 1)) & 3; sA2 = wt + (size_t)(obase_blk + r) * KTOT + sg * 8;
    u = t + 768; r = u >> 2; sg = ((u & 3) - (r >> 1)) & 3; sA3 = wt + (size_t)(obase_blk + r) * KTOT + sg * 8;
  }

  int aU[4], bU[4];
#pragma unroll
  for (int os = 0; os < 4; ++os) { int row = wave * 64 + os * 16 + fr; aU[os] = (4 * row + ((fq + (row >> 1)) & 3)) * 8; }
#pragma unroll
  for (int ps = 0; ps < 4; ++ps) { int row = ps * 16 + fr;             bU[ps] = (4 * row + ((fq + (row >> 1)) & 3)) * 8; }

  float mr = 0.f, rstd = 1.f;
  if (FOLD) {
    float sm = stats_in[n * 2], sq = stats_in[n * 2 + 1];
    float mn = sm * (1.0f / NELF);
    rstd = rsqrtf(sq * (1.0f / NELF) - mn * mn + EPS);
    mr = mn * rstd;
  }

  f32x4 acc[4][4];
#pragma unroll
  for (int a = 0; a < 4; ++a)
#pragma unroll
    for (int b = 0; b < 4; ++b) acc[a][b] = (f32x4){0.f, 0.f, 0.f, 0.f};

  STG(0, 0);
  __syncthreads();
#pragma unroll
  for (int ks = 0; ks < NK; ++ks) {
    const int b = ks & 1;
    if (ks + 1 < NK) STG(b ^ 1, ks + 1);
    bf16x8 afr[4], bfr[4];
#pragma unroll
    for (int os = 0; os < 4; ++os) afr[os] = *(const bf16x8*)&lds[b * 8192 + aU[os]];
#pragma unroll
    for (int ps = 0; ps < 4; ++ps) bfr[ps] = *(const bf16x8*)&lds[16384 + b * 2048 + bU[ps]];
#pragma unroll
    for (int os = 0; os < 4; ++os)
#pragma unroll
      for (int ps = 0; ps < 4; ++ps)
        acc[os][ps] = __builtin_amdgcn_mfma_f32_16x16x32_bf16(afr[os], bfr[ps], acc[os][ps], 0, 0, 0);
    __syncthreads();
  }

  float lsum = 0.f, lsq = 0.f;
  if (EPI != 3) {
#pragma unroll
    for (int os = 0; os < 4; ++os) {
      const int ob = obase_blk + wave * 64 + os * 16 + fq * 4;
      float be[4];
      if (FOLD) {
        float4 g4 = *(const float4*)&Sg[ob];
        float4 s4 = *(const float4*)&Sb[ob];
        be[0] = s4.x - mr * g4.x; be[1] = s4.y - mr * g4.y;
        be[2] = s4.z - mr * g4.z; be[3] = s4.w - mr * g4.w;
      } else {
        float4 s4 = *(const float4*)&Sb[ob];
        be[0] = s4.x; be[1] = s4.y; be[2] = s4.z; be[3] = s4.w;
      }
#pragma unroll
      for (int ps = 0; ps < 4; ++ps) {
        const int pix = ps * 16 + fr;
        u16x4 rv = {0, 0, 0, 0};
        if (EPI == 1 || EPI == 5)
          rv = *(const u16x4*)&residCL[(nHW + hw0 + pix) * 256 + ob];
        u16x4 pk;
#pragma unroll
        for (int j = 0; j < 4; ++j) {
          float v = FOLD ? fmaf(acc[os][ps][j], rstd, be[j]) : (acc[os][ps][j] + be[j]);
          if (EPI == 2 || EPI == 4 || EPI == 5) v = fgelu(v);
          if (EPI == 1 || EPI == 5) v += b2f(rv[j]);
          if (EPI == 0 || EPI == 1 || EPI == 5) { lsum += v; lsq += v * v; }
          pk[j] = (u16)f2bf(v);
        }
        const int qd = wave * 16 + os * 4 + fq;
        const int uq = qd ^ ((pix & 15) << 2);
        *(u16x4*)((char*)lds + pix * 512 + uq * 8) = pk;
      }
    }
    __syncthreads();
    {
      const int p2 = t >> 2;
#pragma unroll
      for (int r = 0; r < 8; ++r) {
        const int oct = (t & 3) + (r << 2);
        const int up = (2 * oct) ^ ((p2 & 15) << 2);
        bf16x8 v = *(const bf16x8*)((char*)lds + p2 * 512 + up * 8);
        *(bf16x8*)&outT[(nHW + hw0 + p2) * OTOT + obase_blk + oct * 8] = v;
      }
    }
  } else {
#pragma unroll
    for (int os = 0; os < 4; ++os) {
      const int ob = wave * 64 + os * 16 + fq * 4;
      float4 b4 = *(const float4*)&Sb[ob];
      float bb[4] = {b4.x, b4.y, b4.z, b4.w};
#pragma unroll
      for (int ps = 0; ps < 4; ++ps) {
        const int pix = ps * 16 + fr;
        u16x4 rv = *(const u16x4*)&residCL[(nHW + hw0 + pix) * 256 + ob];
#pragma unroll
        for (int j = 0; j < 4; ++j)
          out_f32[((size_t)n * 256 + ob + j) * HW + hw0 + pix] = acc[os][ps][j] + bb[j] + b2f(rv[j]);
      }
    }
  }

  if (EPI == 0 || EPI == 1 || EPI == 5) {
    __syncthreads();
    float* red = (float*)lds;
    red[t] = lsum; red[256 + t] = lsq;
    __syncthreads();
    for (int off = 128; off > 0; off >>= 1) {
      if (t < off) { red[t] += red[t + off]; red[256 + t] += red[256 + t + off]; }
      __syncthreads();
    }
    if (t == 0) { atomicAdd(&stats_out[n * 2], red[0]); atomicAdd(&stats_out[n * 2 + 1], red[256]); }
  }
}

extern "C" void kernel_launch(void* const* d_in, const int* in_sizes, int n_in,
                              void* d_out, int out_size, void* d_ws, size_t ws_size,
                              hipStream_t stream) {
  const float* x     = (const float*)d_in[0];
  const float* n1_w  = (const float*)d_in[1];
  const float* n1_b  = (const float*)d_in[2];
  const float* c1_w  = (const float*)d_in[3];
  const float* c1_b  = (const float*)d_in[4];
  const float* an1_w = (const float*)d_in[5];
  const float* an1_b = (const float*)d_in[6];
  const float* c21_w = (const float*)d_in[7];
  const float* c21_b = (const float*)d_in[8];
  const float* c22_w = (const float*)d_in[9];
  const float* c22_b = (const float*)d_in[10];
  const float* an2_w = (const float*)d_in[11];
  const float* an2_b = (const float*)d_in[12];
  const float* c3_w  = (const float*)d_in[13];
  const float* c3_b  = (const float*)d_in[14];
  const float* n2_w  = (const float*)d_in[15];
  const float* n2_b  = (const float*)d_in[16];
  const float* fc1_w = (const float*)d_in[17];
  const float* fc1_b = (const float*)d_in[18];
  const float* fc2_w = (const float*)d_in[19];
  const float* fc2_b = (const float*)d_in[20];

  char* ws = (char*)d_ws;
  float* stats = (float*)ws;                    // 512 B: x, y, z, x2 stat-sets
  float* sums  = (float*)(ws + 1024);           // Sg1,Sb1,Sg3,Sb3 (256 ea), Sgf,Sbf (1024 ea)
  u16* wbuf = (u16*)(ws + 16384);               // 1.57 MB bf16 weights
  u16* wb_c1g  = wbuf;
  u16* wb_c21  = wbuf + 65536;
  u16* wb_c22  = wbuf + 131072;
  u16* wb_c3g  = wbuf + 196608;
  u16* wb_fc1g = wbuf + 262144;
  u16* wb_fc2  = wbuf + 524288;
  const size_t AB = 25690112;                   // bytes per bf16 activation tensor
  char* A0 = ws + 1638400;
  u16* xT  = (u16*)(A0);                        // S0: t0 -> G3 resid
  u16* yT  = (u16*)(A0 + AB);                   // S1: G1 -> e2; reused for zT
  u16* tT  = (u16*)(A0 + 2 * AB);               // S2: e2 -> G2a/b
  u16* zA  = (u16*)(A0 + 3 * AB);               // S3: G2a -> G2b
  u16* zT  = (u16*)(A0 + AB);                   // S1 reuse
  u16* x2T = (u16*)(A0 + 4 * AB);               // S4: G3 -> G4, G5
  u16* hid = (u16*)(A0);                        // S0..S3 overlay (102.76 MB)
  float* out = (float*)d_out;

  hipMemsetAsync(stats, 0, 512, stream);
  wfold_kernel<<<768, 256, 0, stream>>>(c1_w, c21_w, c22_w, c3_w, fc1_w, fc2_w,
                                        n1_w, an2_w, n2_w, wbuf);
  rowsum_kernel<<<6, 256, 0, stream>>>(c1_w, c1_b, n1_w, n1_b, c3_w, c3_b, an2_w, an2_b,
                                       fc1_w, fc1_b, n2_w, n2_b, sums);
  t0_kernel<<<784, 256, 0, stream>>>(x, xT, stats + 0);
  // G1: y = conv1(gn1(x)) -> yT CL, stats(y)
  gemmS<256, 256, 0, 0><<<dim3(784, 1), 256, 0, stream>>>(
      xT, wb_c1g, sums, sums + 256, stats + 0, stats + 32, nullptr, nullptr, yT);
  // E2: t = fgelu(gn_as1(y)) -> tT CL
  e2_kernel<<<2048, 256, 0, stream>>>(yT, tT, an1_w, an1_b, stats + 32);
  // G2a: zA = fgelu(conv21(shift_w(t))) -> CL
  gemmS<256, 256, 1, 4><<<dim3(784, 1), 256, 0, stream>>>(
      tT, wb_c21, nullptr, c21_b, nullptr, nullptr, nullptr, nullptr, zA);
  // G2b: z = fgelu(conv22(shift_h(t))) + zA -> zT CL, stats(z)
  gemmS<256, 256, 2, 5><<<dim3(784, 1), 256, 0, stream>>>(
      tT, wb_c22, nullptr, c22_b, nullptr, stats + 64, zA, nullptr, zT);
  // G3: x2 = xT + conv3(gn_as2(z)) -> x2T CL, stats(x2)
  gemmS<256, 256, 0, 1><<<dim3(784, 1), 256, 0, stream>>>(
      zT, wb_c3g, sums + 512, sums + 768, stats + 64, stats + 96, xT, nullptr, x2T);
  // G4: hid = fgelu(fc1(gn2(x2))) -> CL [pix][1024]
  gemmS<256, 1024, 0, 2><<<dim3(784, 4), 256, 0, stream>>>(
      x2T, wb_fc1g, sums + 1024, sums + 2048, stats + 96, nullptr, nullptr, nullptr, hid);
  // G5: out = x2 + fc2(hid) -> d_out f32 [c][pix]
  gemmS<1024, 256, 0, 3><<<dim3(784, 1), 256, 0, stream>>>(
      hid, wb_fc2, nullptr, fc2_b, nullptr, nullptr, x2T, out, nullptr);
}

// Round 5
// 289.903 us; speedup vs baseline: 1.5489x; 1.0939x over previous
//
#include <hip/hip_runtime.h>

typedef __attribute__((ext_vector_type(4))) float f32x4;
typedef __attribute__((ext_vector_type(8))) short bf16x8;
typedef __attribute__((ext_vector_type(4))) unsigned short u16x4;
typedef unsigned short u16;

#define HW 3136
#define NSEG 49
#define NELF 802816.0f
#define EPS 1e-5f

__device__ __forceinline__ short f2bf(float f) {
  union { float f; unsigned u; } v; v.f = f;
  unsigned r = (v.u + 0x7FFFu + ((v.u >> 16) & 1u)) >> 16;
  return (short)r;
}
__device__ __forceinline__ float b2f(u16 u) {
  union { unsigned u; float f; } v; v.u = ((unsigned)u) << 16;
  return v.f;
}
__device__ __forceinline__ float fgelu(float x) {
  float x2 = x * x;
  float u = x * (0.7978845608f + 0.0356774081f * x2);
  float e = __expf(-2.0f * u);
  return x * __builtin_amdgcn_rcpf(1.0f + e);
}
__device__ __forceinline__ void gload16(const void* g, void* l) {
  __builtin_amdgcn_global_load_lds(
      (const __attribute__((address_space(1))) void*)(uintptr_t)g,
      (__attribute__((address_space(3))) void*)(unsigned)(uintptr_t)l,
      16, 0, 0);
}

// ---- W0a: fold GN column scales into weights, convert to bf16 ----
__global__ void wfold_kernel(const float* __restrict__ c1, const float* __restrict__ c21,
                             const float* __restrict__ c22, const float* __restrict__ c3,
                             const float* __restrict__ fc1, const float* __restrict__ fc2,
                             const float* __restrict__ n1w, const float* __restrict__ an2w,
                             const float* __restrict__ n2w, u16* __restrict__ out) {
  int i = (blockIdx.x * 256 + threadIdx.x) * 4;
  const float* src; int off; const float* scale = nullptr;
  if (i < 65536)       { src = c1;  off = 0;       scale = n1w; }
  else if (i < 131072) { src = c21; off = 65536; }
  else if (i < 196608) { src = c22; off = 131072; }
  else if (i < 262144) { src = c3;  off = 196608;  scale = an2w; }
  else if (i < 524288) { src = fc1; off = 262144;  scale = n2w; }
  else                 { src = fc2; off = 524288; }
  int li = i - off;
  float4 v = *(const float4*)(src + li);
  if (scale) {
    float4 g = *(const float4*)(scale + (li & 255));
    v.x *= g.x; v.y *= g.y; v.z *= g.z; v.w *= g.w;
  }
  u16x4 o4; o4[0] = (u16)f2bf(v.x); o4[1] = (u16)f2bf(v.y); o4[2] = (u16)f2bf(v.z); o4[3] = (u16)f2bf(v.w);
  *(u16x4*)(out + i) = o4;
}

// ---- W0b: Sg/Sb row sums ----
__global__ void rowsum_kernel(const float* __restrict__ c1w, const float* __restrict__ c1b,
                              const float* __restrict__ n1w, const float* __restrict__ n1b,
                              const float* __restrict__ c3w, const float* __restrict__ c3b,
                              const float* __restrict__ an2w, const float* __restrict__ an2b,
                              const float* __restrict__ fc1w, const float* __restrict__ fc1b,
                              const float* __restrict__ n2w, const float* __restrict__ n2b,
                              float* __restrict__ sums) {
  int o = blockIdx.x * 256 + threadIdx.x;
  const float *W, *gw, *gb, *cb; float *Sg, *Sb; int row;
  if (o < 256)      { W = c1w;  gw = n1w;  gb = n1b;  cb = c1b;  Sg = sums;        Sb = sums + 256;  row = o; }
  else if (o < 512) { W = c3w;  gw = an2w; gb = an2b; cb = c3b;  Sg = sums + 512;  Sb = sums + 768;  row = o - 256; }
  else              { W = fc1w; gw = n2w;  gb = n2b;  cb = fc1b; Sg = sums + 1024; Sb = sums + 2048; row = o - 512; }
  float sg = 0.f, sb = 0.f;
  for (int c = 0; c < 256; c += 4) {
    float4 w = *(const float4*)(W + (size_t)row * 256 + c);
    float4 g = *(const float4*)(gw + c);
    float4 b = *(const float4*)(gb + c);
    sg += w.x * g.x + w.y * g.y + w.z * g.z + w.w * g.w;
    sb += w.x * b.x + w.y * b.y + w.z * b.z + w.w * b.w;
  }
  Sg[row] = sg; Sb[row] = sb + cb[row];
}

// ---- T0: stats(x) + transpose x -> xT bf16 [n][pix][c] ----
__global__ __launch_bounds__(256) void t0_kernel(const float* __restrict__ x,
                                                 u16* __restrict__ xT, float* __restrict__ st) {
  __shared__ __align__(16) u16 tile[64 * 256];
  const int t = threadIdx.x;
  const int n = blockIdx.x / NSEG;
  const int hw0 = (blockIdx.x % NSEG) * 64;
  const int pix = t & 63;
  float s = 0.f, q = 0.f;
#pragma unroll
  for (int r = 0; r < 16; ++r) {
    int cq = (t >> 6) + (r << 2);
    int c = cq * 4;
    u16x4 o4;
#pragma unroll
    for (int i = 0; i < 4; ++i) {
      float v = x[((size_t)n * 256 + c + i) * HW + hw0 + pix];
      s += v; q += v * v;
      o4[i] = (u16)f2bf(v);
    }
    int u = cq ^ ((pix & 15) << 2);
    *(u16x4*)((char*)tile + pix * 512 + u * 8) = o4;
  }
  __syncthreads();
  {
    const int p2 = t >> 2;
#pragma unroll
    for (int r = 0; r < 8; ++r) {
      int oct = (t & 3) + (r << 2);
      int up = (2 * oct) ^ ((p2 & 15) << 2);
      bf16x8 v = *(const bf16x8*)((char*)tile + p2 * 512 + up * 8);
      *(bf16x8*)&xT[((size_t)n * HW + hw0 + p2) * 256 + oct * 8] = v;
    }
  }
  __syncthreads();
  float* red = (float*)tile;
  red[t] = s; red[256 + t] = q;
  __syncthreads();
  for (int off = 128; off > 0; off >>= 1) {
    if (t < off) { red[t] += red[t + off]; red[256 + t] += red[256 + t + off]; }
    __syncthreads();
  }
  if (t == 0) { atomicAdd(&st[n * 2], red[0]); atomicAdd(&st[n * 2 + 1], red[256]); }
}

// ---- E2: t = fgelu(gn_as1(y)), channel-last elementwise ----
__global__ void e2_kernel(const u16* __restrict__ y, u16* __restrict__ tb,
                          const float* __restrict__ gw, const float* __restrict__ gb,
                          const float* __restrict__ stats) {
  const size_t NG = (size_t)16 * HW * 32;
  for (size_t g = (size_t)blockIdx.x * blockDim.x + threadIdx.x; g < NG;
       g += (size_t)gridDim.x * blockDim.x) {
    size_t base = g * 8;
    int n = (int)(base / 802816);
    int c0 = (int)(base & 255);
    float sm = stats[n * 2], sq = stats[n * 2 + 1];
    float mn = sm * (1.0f / NELF);
    float rstd = rsqrtf(sq * (1.0f / NELF) - mn * mn + EPS);
    bf16x8 v = *(const bf16x8*)(y + base);
    bf16x8 o;
#pragma unroll
    for (int j = 0; j < 8; ++j) {
      float sc = rstd * gw[c0 + j];
      float sh = gb[c0 + j] - mn * sc;
      o[j] = f2bf(fgelu(b2f((u16)v[j]) * sc + sh));
    }
    *(bf16x8*)(tb + base) = o;
  }
}

// ---- gemmW: weights resident in LDS, 512 thr, tile 256 out x 224 pix, K=256 ----
// PRO: 0 none; 1 shift_w; 2 shift_h (reg-staged B with shift fold)
// EPI: 0 fold+stats | 1 fold+resid+stats | 2 fold+gelu | 4 bias+gelu | 5 bias+gelu+resid+stats
template<int PRO, int EPI, int OTOT>
__global__ __launch_bounds__(512, 2) void gemmW(
    const u16* __restrict__ actT, const u16* __restrict__ wt,
    const float* __restrict__ Sg, const float* __restrict__ Sb,
    const float* __restrict__ stats_in, float* __restrict__ stats_out,
    const u16* __restrict__ residCL, u16* __restrict__ outT)
{
  constexpr bool FOLD = (EPI == 0 || EPI == 1 || EPI == 2);
  __shared__ __align__(16) u16 lds[72704];   // W: [0,65536) ; B: [65536,72704)  = 145408 B
  const int t = threadIdx.x;
  const int lane = t & 63, wave = t >> 6;
  const int fr = lane & 15, fq = lane >> 4;
  const int wo = wave >> 1, wp = wave & 1;
  const int n = blockIdx.x / 14;
  const int hw0 = (blockIdx.x % 14) * 224;
  const int obase = blockIdx.y << 8;
  const size_t nHW = (size_t)n * HW;

  // ---- W prologue staging (16 gload16/thread) ----
  {
    int u0 = t, u1 = t + 512;
    int r0 = u0 >> 2, sg0 = ((u0 & 3) - (r0 >> 1)) & 3;
    int r1 = u1 >> 2, sg1 = ((u1 & 3) - (r1 >> 1)) & 3;
    const u16* w0 = wt + (size_t)(obase + r0) * 256 + sg0 * 8;
    const u16* w1 = wt + (size_t)(obase + r1) * 256 + sg1 * 8;
#pragma unroll
    for (int k = 0; k < 8; ++k) {
      gload16(w0 + k * 32, &lds[k * 8192 + wave * 512]);
      gload16(w1 + k * 32, &lds[k * 8192 + 4096 + wave * 512]);
    }
  }

  // ---- B reg-staging setup: t<448, row=t>>1, units j0,j0+1 ----
  const bool bact = (t < 448);
  const int brow = t >> 1;
  const int bp = hw0 + brow;
  int bwp = 0;
  if (PRO == 1) bwp = bp % 56;
  if (PRO == 2) bwp = bp / 56;
  const int bj0 = (t & 1) * 2;
  const u16* bsrc = actT + (nHW + bp) * 256;

  auto loadBu = [&](int c0, bf16x8& v) {
    if (PRO == 0) {
      v = *(const bf16x8*)(bsrc + c0);
    } else {
      int g0 = c0 / 37;
      int js = (g0 + 1) * 37 - c0;
      int s0 = 3 - g0;
      if (js >= 8) {
        if ((unsigned)(bwp + s0) < 56u) {
          int dp = (PRO == 1) ? s0 : 56 * s0;
          v = *(const bf16x8*)(bsrc + dp * 256 + c0);
        } else {
          v = (bf16x8){0, 0, 0, 0, 0, 0, 0, 0};
        }
      } else {
#pragma unroll
        for (int j = 0; j < 8; ++j) {
          int s = s0 - (j >= js ? 1 : 0);
          int dp = (PRO == 1) ? s : 56 * s;
          int pp = bp + dp; pp = pp < 0 ? 0 : (pp > HW - 1 ? HW - 1 : pp);
          u16 uv = actT[(nHW + pp) * 256 + c0 + j];
          v[j] = ((unsigned)(bwp + s) < 56u) ? (short)uv : (short)0;
        }
      }
    }
  };

  int aU[4], bO[7];
#pragma unroll
  for (int os = 0; os < 4; ++os) { int row = wo * 64 + os * 16 + fr; aU[os] = (4 * row + ((fq + (row >> 1)) & 3)) * 8; }
#pragma unroll
  for (int ps = 0; ps < 7; ++ps) bO[ps] = 65536 + (fq * 224 + wp * 112 + ps * 16 + fr) * 8;

  f32x4 acc[4][7];
#pragma unroll
  for (int a = 0; a < 4; ++a)
#pragma unroll
    for (int b = 0; b < 7; ++b) acc[a][b] = (f32x4){0.f, 0.f, 0.f, 0.f};

  // prologue B (kstep 0)
  {
    bf16x8 v0, v1;
    if (bact) { loadBu(bj0 * 8, v0); loadBu(bj0 * 8 + 8, v1); }
    asm volatile("s_waitcnt vmcnt(0)" ::: "memory");   // W DMA landed
    if (bact) {
      *(bf16x8*)&lds[65536 + (bj0 * 224 + brow) * 8] = v0;
      *(bf16x8*)&lds[65536 + ((bj0 + 1) * 224 + brow) * 8] = v1;
    }
  }
  __syncthreads();

#pragma unroll
  for (int k = 0; k < 8; ++k) {
    bf16x8 n0, n1;
    if (k < 7 && bact) { loadBu((k + 1) * 32 + bj0 * 8, n0); loadBu((k + 1) * 32 + bj0 * 8 + 8, n1); }
    bf16x8 afr[4], bfr[7];
#pragma unroll
    for (int os = 0; os < 4; ++os) afr[os] = *(const bf16x8*)&lds[k * 8192 + aU[os]];
#pragma unroll
    for (int ps = 0; ps < 7; ++ps) bfr[ps] = *(const bf16x8*)&lds[bO[ps]];
#pragma unroll
    for (int os = 0; os < 4; ++os)
#pragma unroll
      for (int ps = 0; ps < 7; ++ps)
        acc[os][ps] = __builtin_amdgcn_mfma_f32_16x16x32_bf16(afr[os], bfr[ps], acc[os][ps], 0, 0, 0);
    __builtin_amdgcn_s_barrier();          // all reads of B-plane done
    if (k < 7) {
      if (bact) {
        *(bf16x8*)&lds[65536 + (bj0 * 224 + brow) * 8] = n0;
        *(bf16x8*)&lds[65536 + ((bj0 + 1) * 224 + brow) * 8] = n1;
      }
      asm volatile("s_waitcnt lgkmcnt(0)" ::: "memory");
      __builtin_amdgcn_sched_barrier(0);
      __builtin_amdgcn_s_barrier();        // B-plane refilled, visible
    }
  }
  __syncthreads();

  // ---- epilogue: LDS transpose to channel-last ----
  char* tl = (char*)lds;
  float mr = 0.f, rstd = 1.f;
  if (FOLD) {
    float sm = stats_in[n * 2], sq = stats_in[n * 2 + 1];
    float mn = sm * (1.0f / NELF);
    rstd = rsqrtf(sq * (1.0f / NELF) - mn * mn + EPS);
    mr = mn * rstd;
  }
  float lsum = 0.f, lsq = 0.f;
#pragma unroll
  for (int os = 0; os < 4; ++os) {
    const int obl = wo * 64 + os * 16 + fq * 4;
    const int ob = obase + obl;
    float be[4];
    if (FOLD) {
      float4 g4 = *(const float4*)&Sg[ob];
      float4 s4 = *(const float4*)&Sb[ob];
      be[0] = s4.x - mr * g4.x; be[1] = s4.y - mr * g4.y;
      be[2] = s4.z - mr * g4.z; be[3] = s4.w - mr * g4.w;
    } else {
      float4 s4 = *(const float4*)&Sb[obl];
      be[0] = s4.x; be[1] = s4.y; be[2] = s4.z; be[3] = s4.w;
    }
#pragma unroll
    for (int ps = 0; ps < 7; ++ps) {
      const int pix = wp * 112 + ps * 16 + fr;
      u16x4 rv = {0, 0, 0, 0};
      if (EPI == 1 || EPI == 5)
        rv = *(const u16x4*)&residCL[(nHW + hw0 + pix) * 256 + obl];
      u16x4 pk;
#pragma unroll
      for (int j = 0; j < 4; ++j) {
        float v = FOLD ? fmaf(acc[os][ps][j], rstd, be[j]) : (acc[os][ps][j] + be[j]);
        if (EPI == 2 || EPI == 4 || EPI == 5) v = fgelu(v);
        if (EPI == 1 || EPI == 5) v += b2f(rv[j]);
        if (EPI == 0 || EPI == 1 || EPI == 5) { lsum += v; lsq += v * v; }
        pk[j] = (u16)f2bf(v);
      }
      const int qd = wo * 16 + os * 4 + fq;
      const int uq = qd ^ ((pix & 15) << 2);
      *(u16x4*)(tl + pix * 512 + uq * 8) = pk;
    }
  }
  __syncthreads();
#pragma unroll
  for (int r = 0; r < 14; ++r) {
    int idx = t + r * 512;
    int pix = idx >> 5, oct = idx & 31;
    int up = (2 * oct) ^ ((pix & 15) << 2);
    bf16x8 v = *(const bf16x8*)(tl + pix * 512 + up * 8);
    *(bf16x8*)&outT[(nHW + hw0 + pix) * OTOT + obase + oct * 8] = v;
  }

  if (EPI == 0 || EPI == 1 || EPI == 5) {
    __syncthreads();
    float* red = (float*)lds;
    red[t] = lsum; red[512 + t] = lsq;
    __syncthreads();
    for (int off = 256; off > 0; off >>= 1) {
      if (t < off) { red[t] += red[t + off]; red[512 + t] += red[512 + t + off]; }
      __syncthreads();
    }
    if (t == 0) { atomicAdd(&stats_out[n * 2], red[0]); atomicAdd(&stats_out[n * 2 + 1], red[512]); }
  }
}

// ---- gemmF: G5, K=1024 double-buffered, 512 thr, 256 out x 224 pix ----
__global__ __launch_bounds__(512, 2) void gemmF(
    const u16* __restrict__ hidT, const u16* __restrict__ wt,
    const float* __restrict__ bias, const u16* __restrict__ residCL,
    float* __restrict__ out_f32)
{
  __shared__ __align__(16) u16 lds[30720];  // A: 2x8192, B: 16384 + 2x7168
  const int t = threadIdx.x;
  const int lane = t & 63, wave = t >> 6;
  const int fr = lane & 15, fq = lane >> 4;
  const int wo = wave >> 1, wp = wave & 1;
  const int n = blockIdx.x / 14;
  const int hw0 = (blockIdx.x % 14) * 224;
  const size_t nHW = (size_t)n * HW;

  int u0 = t, u1 = t + 512;
  int r0 = u0 >> 2, sg0 = ((u0 & 3) - (r0 >> 1)) & 3;
  int r1 = u1 >> 2, sg1 = ((u1 & 3) - (r1 >> 1)) & 3;
  const u16* wA0 = wt + (size_t)r0 * 1024 + sg0 * 8;
  const u16* wA1 = wt + (size_t)r1 * 1024 + sg1 * 8;
  const int c1 = (2 * wave) % 14, c2 = (2 * wave + 1) % 14;
  const int ub1 = c1 * 64 + lane, ub2 = c2 * 64 + lane;
  const u16* hb1 = hidT + (nHW + hw0 + ub1 % 224) * 1024 + (ub1 / 224) * 8;
  const u16* hb2 = hidT + (nHW + hw0 + ub2 % 224) * 1024 + (ub2 / 224) * 8;

  auto stgf = [&](int bs, int k0) {
    gload16(wA0 + k0, &lds[bs * 8192 + wave * 512]);
    gload16(wA1 + k0, &lds[bs * 8192 + 4096 + wave * 512]);
    gload16(hb1 + k0, &lds[16384 + bs * 7168 + c1 * 512]);
    gload16(hb2 + k0, &lds[16384 + bs * 7168 + c2 * 512]);
  };

  int aU[4], bO[7];
#pragma unroll
  for (int os = 0; os < 4; ++os) { int row = wo * 64 + os * 16 + fr; aU[os] = (4 * row + ((fq + (row >> 1)) & 3)) * 8; }
#pragma unroll
  for (int ps = 0; ps < 7; ++ps) bO[ps] = 16384 + (fq * 224 + wp * 112 + ps * 16 + fr) * 8;

  f32x4 acc[4][7];
#pragma unroll
  for (int a = 0; a < 4; ++a)
#pragma unroll
    for (int b = 0; b < 7; ++b) acc[a][b] = (f32x4){0.f, 0.f, 0.f, 0.f};

  stgf(0, 0);
  __syncthreads();
  for (int ks = 0; ks < 32; ++ks) {
    const int bs = ks & 1;
    if (ks < 31) stgf(bs ^ 1, (ks + 1) * 32);
    bf16x8 afr[4], bfr[7];
#pragma unroll
    for (int os = 0; os < 4; ++os) afr[os] = *(const bf16x8*)&lds[bs * 8192 + aU[os]];
#pragma unroll
    for (int ps = 0; ps < 7; ++ps) bfr[ps] = *(const bf16x8*)&lds[bs * 7168 + bO[ps]];
#pragma unroll
    for (int os = 0; os < 4; ++os)
#pragma unroll
      for (int ps = 0; ps < 7; ++ps)
        acc[os][ps] = __builtin_amdgcn_mfma_f32_16x16x32_bf16(afr[os], bfr[ps], acc[os][ps], 0, 0, 0);
    __syncthreads();
  }

#pragma unroll
  for (int os = 0; os < 4; ++os) {
    const int ob = wo * 64 + os * 16 + fq * 4;
    float4 b4 = *(const float4*)&bias[ob];
    float bb[4] = {b4.x, b4.y, b4.z, b4.w};
#pragma unroll
    for (int ps = 0; ps < 7; ++ps) {
      const int pix = wp * 112 + ps * 16 + fr;
      u16x4 rv = *(const u16x4*)&residCL[(nHW + hw0 + pix) * 256 + ob];
#pragma unroll
      for (int j = 0; j < 4; ++j)
        out_f32[((size_t)n * 256 + ob + j) * HW + hw0 + pix] = acc[os][ps][j] + bb[j] + b2f(rv[j]);
    }
  }
}

extern "C" void kernel_launch(void* const* d_in, const int* in_sizes, int n_in,
                              void* d_out, int out_size, void* d_ws, size_t ws_size,
                              hipStream_t stream) {
  const float* x     = (const float*)d_in[0];
  const float* n1_w  = (const float*)d_in[1];
  const float* n1_b  = (const float*)d_in[2];
  const float* c1_w  = (const float*)d_in[3];
  const float* c1_b  = (const float*)d_in[4];
  const float* an1_w = (const float*)d_in[5];
  const float* an1_b = (const float*)d_in[6];
  const float* c21_w = (const float*)d_in[7];
  const float* c21_b = (const float*)d_in[8];
  const float* c22_w = (const float*)d_in[9];
  const float* c22_b = (const float*)d_in[10];
  const float* an2_w = (const float*)d_in[11];
  const float* an2_b = (const float*)d_in[12];
  const float* c3_w  = (const float*)d_in[13];
  const float* c3_b  = (const float*)d_in[14];
  const float* n2_w  = (const float*)d_in[15];
  const float* n2_b  = (const float*)d_in[16];
  const float* fc1_w = (const float*)d_in[17];
  const float* fc1_b = (const float*)d_in[18];
  const float* fc2_w = (const float*)d_in[19];
  const float* fc2_b = (const float*)d_in[20];

  char* ws = (char*)d_ws;
  float* stats = (float*)ws;
  float* sums  = (float*)(ws + 1024);
  u16* wbuf = (u16*)(ws + 16384);
  u16* wb_c1g  = wbuf;
  u16* wb_c21  = wbuf + 65536;
  u16* wb_c22  = wbuf + 131072;
  u16* wb_c3g  = wbuf + 196608;
  u16* wb_fc1g = wbuf + 262144;
  u16* wb_fc2  = wbuf + 524288;
  const size_t AB = 25690112;
  char* A0 = ws + 1638400;
  u16* xT  = (u16*)(A0);
  u16* yT  = (u16*)(A0 + AB);
  u16* tT  = (u16*)(A0 + 2 * AB);
  u16* zA  = (u16*)(A0 + 3 * AB);
  u16* zT  = (u16*)(A0 + AB);
  u16* x2T = (u16*)(A0 + 4 * AB);
  u16* hid = (u16*)(A0);
  float* out = (float*)d_out;

  hipMemsetAsync(stats, 0, 512, stream);
  wfold_kernel<<<768, 256, 0, stream>>>(c1_w, c21_w, c22_w, c3_w, fc1_w, fc2_w,
                                        n1_w, an2_w, n2_w, wbuf);
  rowsum_kernel<<<6, 256, 0, stream>>>(c1_w, c1_b, n1_w, n1_b, c3_w, c3_b, an2_w, an2_b,
                                       fc1_w, fc1_b, n2_w, n2_b, sums);
  t0_kernel<<<784, 256, 0, stream>>>(x, xT, stats + 0);
  // G1: y = conv1(gn1(x)) -> yT CL, stats(y)
  gemmW<0, 0, 256><<<dim3(224, 1), 512, 0, stream>>>(
      xT, wb_c1g, sums, sums + 256, stats + 0, stats + 32, nullptr, yT);
  // E2: t = fgelu(gn_as1(y)) -> tT CL
  e2_kernel<<<2048, 256, 0, stream>>>(yT, tT, an1_w, an1_b, stats + 32);
  // G2a: zA = fgelu(conv21(shift_w(t))) -> CL
  gemmW<1, 4, 256><<<dim3(224, 1), 512, 0, stream>>>(
      tT, wb_c21, nullptr, c21_b, nullptr, nullptr, nullptr, zA);
  // G2b: z = fgelu(conv22(shift_h(t))) + zA -> zT CL, stats(z)
  gemmW<2, 5, 256><<<dim3(224, 1), 512, 0, stream>>>(
      tT, wb_c22, nullptr, c22_b, nullptr, stats + 64, zA, zT);
  // G3: x2 = xT + conv3(gn_as2(z)) -> x2T CL, stats(x2)
  gemmW<0, 1, 256><<<dim3(224, 1), 512, 0, stream>>>(
      zT, wb_c3g, sums + 512, sums + 768, stats + 64, stats + 96, xT, x2T);
  // G4: hid = fgelu(fc1(gn2(x2))) -> hid CL [pix][1024]
  gemmW<0, 2, 1024><<<dim3(224, 4), 512, 0, stream>>>(
      x2T, wb_fc1g, sums + 1024, sums + 2048, stats + 96, nullptr, nullptr, hid);
  // G5: out = x2 + fc2(hid) -> d_out f32 [c][pix]
  gemmF<<<224, 512, 0, stream>>>(hid, wb_fc2, fc2_b, x2T, out);
}

// Round 6
// 286.198 us; speedup vs baseline: 1.5690x; 1.0129x over previous
//
#include <hip/hip_runtime.h>

typedef __attribute__((ext_vector_type(4))) float f32x4;
typedef __attribute__((ext_vector_type(8))) short bf16x8;
typedef __attribute__((ext_vector_type(4))) unsigned short u16x4;
typedef unsigned short u16;

#define HW 3136
#define NSEG 49
#define NELF 802816.0f
#define EPS 1e-5f

__device__ __forceinline__ short f2bf(float f) {
  union { float f; unsigned u; } v; v.f = f;
  unsigned r = (v.u + 0x7FFFu + ((v.u >> 16) & 1u)) >> 16;
  return (short)r;
}
__device__ __forceinline__ float b2f(u16 u) {
  union { unsigned u; float f; } v; v.u = ((unsigned)u) << 16;
  return v.f;
}
__device__ __forceinline__ float fgelu(float x) {
  float x2 = x * x;
  float u = x * (0.7978845608f + 0.0356774081f * x2);
  float e = __expf(-2.0f * u);
  return x * __builtin_amdgcn_rcpf(1.0f + e);
}
__device__ __forceinline__ void gload16(const void* g, void* l) {
  __builtin_amdgcn_global_load_lds(
      (const __attribute__((address_space(1))) void*)(uintptr_t)g,
      (__attribute__((address_space(3))) void*)(unsigned)(uintptr_t)l,
      16, 0, 0);
}

// ---- W0a: fold GN column scales into weights, convert to bf16 ----
__global__ void wfold_kernel(const float* __restrict__ c1, const float* __restrict__ c21,
                             const float* __restrict__ c22, const float* __restrict__ c3,
                             const float* __restrict__ fc1, const float* __restrict__ fc2,
                             const float* __restrict__ n1w, const float* __restrict__ an2w,
                             const float* __restrict__ n2w, u16* __restrict__ out) {
  int i = (blockIdx.x * 256 + threadIdx.x) * 4;
  const float* src; int off; const float* scale = nullptr;
  if (i < 65536)       { src = c1;  off = 0;       scale = n1w; }
  else if (i < 131072) { src = c21; off = 65536; }
  else if (i < 196608) { src = c22; off = 131072; }
  else if (i < 262144) { src = c3;  off = 196608;  scale = an2w; }
  else if (i < 524288) { src = fc1; off = 262144;  scale = n2w; }
  else                 { src = fc2; off = 524288; }
  int li = i - off;
  float4 v = *(const float4*)(src + li);
  if (scale) {
    float4 g = *(const float4*)(scale + (li & 255));
    v.x *= g.x; v.y *= g.y; v.z *= g.z; v.w *= g.w;
  }
  u16x4 o4; o4[0] = (u16)f2bf(v.x); o4[1] = (u16)f2bf(v.y); o4[2] = (u16)f2bf(v.z); o4[3] = (u16)f2bf(v.w);
  *(u16x4*)(out + i) = o4;
}

// ---- W0b: Sg/Sb row sums ----
__global__ void rowsum_kernel(const float* __restrict__ c1w, const float* __restrict__ c1b,
                              const float* __restrict__ n1w, const float* __restrict__ n1b,
                              const float* __restrict__ c3w, const float* __restrict__ c3b,
                              const float* __restrict__ an2w, const float* __restrict__ an2b,
                              const float* __restrict__ fc1w, const float* __restrict__ fc1b,
                              const float* __restrict__ n2w, const float* __restrict__ n2b,
                              float* __restrict__ sums) {
  int o = blockIdx.x * 256 + threadIdx.x;
  const float *W, *gw, *gb, *cb; float *Sg, *Sb; int row;
  if (o < 256)      { W = c1w;  gw = n1w;  gb = n1b;  cb = c1b;  Sg = sums;        Sb = sums + 256;  row = o; }
  else if (o < 512) { W = c3w;  gw = an2w; gb = an2b; cb = c3b;  Sg = sums + 512;  Sb = sums + 768;  row = o - 256; }
  else              { W = fc1w; gw = n2w;  gb = n2b;  cb = fc1b; Sg = sums + 1024; Sb = sums + 2048; row = o - 512; }
  float sg = 0.f, sb = 0.f;
  for (int c = 0; c < 256; c += 4) {
    float4 w = *(const float4*)(W + (size_t)row * 256 + c);
    float4 g = *(const float4*)(gw + c);
    float4 b = *(const float4*)(gb + c);
    sg += w.x * g.x + w.y * g.y + w.z * g.z + w.w * g.w;
    sb += w.x * b.x + w.y * b.y + w.z * b.z + w.w * b.w;
  }
  Sg[row] = sg; Sb[row] = sb + cb[row];
}

// ---- T0: stats(x) + transpose x -> xT bf16 [n][pix][c] ----
__global__ __launch_bounds__(256) void t0_kernel(const float* __restrict__ x,
                                                 u16* __restrict__ xT, float* __restrict__ st) {
  __shared__ __align__(16) u16 tile[64 * 256];
  const int t = threadIdx.x;
  const int n = blockIdx.x / NSEG;
  const int hw0 = (blockIdx.x % NSEG) * 64;
  const int pix = t & 63;
  float s = 0.f, q = 0.f;
#pragma unroll
  for (int r = 0; r < 16; ++r) {
    int cq = (t >> 6) + (r << 2);
    int c = cq * 4;
    u16x4 o4;
#pragma unroll
    for (int i = 0; i < 4; ++i) {
      float v = x[((size_t)n * 256 + c + i) * HW + hw0 + pix];
      s += v; q += v * v;
      o4[i] = (u16)f2bf(v);
    }
    int u = cq ^ ((pix & 15) << 2);
    *(u16x4*)((char*)tile + pix * 512 + u * 8) = o4;
  }
  __syncthreads();
  {
    const int p2 = t >> 2;
#pragma unroll
    for (int r = 0; r < 8; ++r) {
      int oct = (t & 3) + (r << 2);
      int up = (2 * oct) ^ ((p2 & 15) << 2);
      bf16x8 v = *(const bf16x8*)((char*)tile + p2 * 512 + up * 8);
      *(bf16x8*)&xT[((size_t)n * HW + hw0 + p2) * 256 + oct * 8] = v;
    }
  }
  __syncthreads();
  float* red = (float*)tile;
  red[t] = s; red[256 + t] = q;
  __syncthreads();
  for (int off = 128; off > 0; off >>= 1) {
    if (t < off) { red[t] += red[t + off]; red[256 + t] += red[256 + t + off]; }
    __syncthreads();
  }
  if (t == 0) { atomicAdd(&st[n * 2], red[0]); atomicAdd(&st[n * 2 + 1], red[256]); }
}

// ---- E2: t = fgelu(gn_as1(y)), channel-last elementwise ----
__global__ void e2_kernel(const u16* __restrict__ y, u16* __restrict__ tb,
                          const float* __restrict__ gw, const float* __restrict__ gb,
                          const float* __restrict__ stats) {
  const size_t NG = (size_t)16 * HW * 32;
  for (size_t g = (size_t)blockIdx.x * blockDim.x + threadIdx.x; g < NG;
       g += (size_t)gridDim.x * blockDim.x) {
    size_t base = g * 8;
    int n = (int)(base / 802816);
    int c0 = (int)(base & 255);
    float sm = stats[n * 2], sq = stats[n * 2 + 1];
    float mn = sm * (1.0f / NELF);
    float rstd = rsqrtf(sq * (1.0f / NELF) - mn * mn + EPS);
    bf16x8 v = *(const bf16x8*)(y + base);
    bf16x8 o;
#pragma unroll
    for (int j = 0; j < 8; ++j) {
      float sc = rstd * gw[c0 + j];
      float sh = gb[c0 + j] - mn * sc;
      o[j] = f2bf(fgelu(b2f((u16)v[j]) * sc + sh));
    }
    *(bf16x8*)(tb + base) = o;
  }
}

// ---- gemmW2: W resident in LDS, B via DMA dbuf, 512 thr, 256 out x 224 pix ----
// EPI: 0 = y (fold + store CL + stats) | 1 = x2 (fold + resid + store CL + stats)
template<int EPI>
__global__ __launch_bounds__(512, 2) void gemmW2(
    const u16* __restrict__ actT, const u16* __restrict__ wt,
    const float* __restrict__ Sg, const float* __restrict__ Sb,
    const float* __restrict__ stats_in, float* __restrict__ stats_out,
    const u16* __restrict__ residCL, u16* __restrict__ outT)
{
  __shared__ __align__(16) u16 lds[79872];   // W [0,65536); B dbuf [65536,72704),[72704,79872)
  const int t = threadIdx.x;
  const int lane = t & 63, wave = t >> 6;
  const int fr = lane & 15, fq = lane >> 4;
  const int wo = wave >> 1, wp = wave & 1;
  const int n = blockIdx.x / 14;
  const int hw0 = (blockIdx.x % 14) * 224;
  const size_t nHW = (size_t)n * HW;

  // W prologue
  {
    int u0 = t, u1 = t + 512;
    int r0 = u0 >> 2, sg0 = ((u0 & 3) - (r0 >> 1)) & 3;
    int r1 = u1 >> 2, sg1 = ((u1 & 3) - (r1 >> 1)) & 3;
    const u16* w0 = wt + (size_t)r0 * 256 + sg0 * 8;
    const u16* w1 = wt + (size_t)r1 * 256 + sg1 * 8;
#pragma unroll
    for (int k = 0; k < 8; ++k) {
      gload16(w0 + k * 32, &lds[k * 8192 + wave * 512]);
      gload16(w1 + k * 32, &lds[k * 8192 + 4096 + wave * 512]);
    }
  }

  int aU[4], bO[7];
#pragma unroll
  for (int os = 0; os < 4; ++os) { int row = wo * 64 + os * 16 + fr; aU[os] = (4 * row + ((fq + (row >> 1)) & 3)) * 8; }
#pragma unroll
  for (int ps = 0; ps < 7; ++ps) bO[ps] = (fq * 224 + wp * 112 + ps * 16 + fr) * 8;

  // B staging: waves 0..6 stage 2 units (1KB DMA each); unit u -> (j=u/224, p=u%224)
  auto stageB = [&](int par, int ks) {
    if (wave < 7) {
#pragma unroll
      for (int i = 0; i < 2; ++i) {
        int ub = wave * 128 + i * 64;
        int u = ub + lane;
        int j = u / 224, p = u - j * 224;
        gload16(actT + (nHW + hw0 + p) * 256 + ks * 32 + j * 8,
                &lds[65536 + par * 7168 + ub * 8]);
      }
    }
  };

  f32x4 acc[4][7];
#pragma unroll
  for (int a = 0; a < 4; ++a)
#pragma unroll
    for (int b = 0; b < 7; ++b) acc[a][b] = (f32x4){0.f, 0.f, 0.f, 0.f};

  stageB(0, 0);
  __syncthreads();

#pragma unroll
  for (int k = 0; k < 8; ++k) {
    if (k < 7) stageB((k + 1) & 1, k + 1);
    bf16x8 afr[4], bfr[7];
#pragma unroll
    for (int os = 0; os < 4; ++os) afr[os] = *(const bf16x8*)&lds[k * 8192 + aU[os]];
#pragma unroll
    for (int ps = 0; ps < 7; ++ps) bfr[ps] = *(const bf16x8*)&lds[65536 + (k & 1) * 7168 + bO[ps]];
#pragma unroll
    for (int os = 0; os < 4; ++os)
#pragma unroll
      for (int ps = 0; ps < 7; ++ps)
        acc[os][ps] = __builtin_amdgcn_mfma_f32_16x16x32_bf16(afr[os], bfr[ps], acc[os][ps], 0, 0, 0);
    __syncthreads();
  }

  // epilogue: fold + (resid) + transpose store CL + stats
  char* tl = (char*)lds;
  float sm = stats_in[n * 2], sq = stats_in[n * 2 + 1];
  float mn = sm * (1.0f / NELF);
  float rstd = rsqrtf(sq * (1.0f / NELF) - mn * mn + EPS);
  float mr = mn * rstd;
  float lsum = 0.f, lsq = 0.f;
#pragma unroll
  for (int os = 0; os < 4; ++os) {
    const int ob = wo * 64 + os * 16 + fq * 4;
    float4 g4 = *(const float4*)&Sg[ob];
    float4 s4 = *(const float4*)&Sb[ob];
    float be[4] = {s4.x - mr * g4.x, s4.y - mr * g4.y, s4.z - mr * g4.z, s4.w - mr * g4.w};
#pragma unroll
    for (int ps = 0; ps < 7; ++ps) {
      const int pix = wp * 112 + ps * 16 + fr;
      u16x4 rv = {0, 0, 0, 0};
      if (EPI == 1) rv = *(const u16x4*)&residCL[(nHW + hw0 + pix) * 256 + ob];
      u16x4 pk;
#pragma unroll
      for (int j = 0; j < 4; ++j) {
        float v = fmaf(acc[os][ps][j], rstd, be[j]);
        if (EPI == 1) v += b2f(rv[j]);
        lsum += v; lsq += v * v;
        pk[j] = (u16)f2bf(v);
      }
      const int qd = wo * 16 + os * 4 + fq;
      const int uq = qd ^ ((pix & 15) << 2);
      *(u16x4*)(tl + pix * 512 + uq * 8) = pk;
    }
  }
  __syncthreads();
#pragma unroll
  for (int r = 0; r < 14; ++r) {
    int idx = t + r * 512;
    int pix = idx >> 5, oct = idx & 31;
    int up = (2 * oct) ^ ((pix & 15) << 2);
    bf16x8 v = *(const bf16x8*)(tl + pix * 512 + up * 8);
    *(bf16x8*)&outT[(nHW + hw0 + pix) * 256 + oct * 8] = v;
  }
  __syncthreads();
  float* red = (float*)lds;
  red[t] = lsum; red[512 + t] = lsq;
  __syncthreads();
  for (int off = 256; off > 0; off >>= 1) {
    if (t < off) { red[t] += red[t + off]; red[512 + t] += red[512 + t + off]; }
    __syncthreads();
  }
  if (t == 0) { atomicAdd(&stats_out[n * 2], red[0]); atomicAdd(&stats_out[n * 2 + 1], red[512]); }
}

// ---- gemm_dual4: z = fgelu(conv21(shift_w t)) + fgelu(conv22(shift_h t)), 256 out x 112 pix ----
__global__ __launch_bounds__(512, 2) void gemm_dual4(
    const u16* __restrict__ tT, const u16* __restrict__ w21, const u16* __restrict__ w22,
    const float* __restrict__ b21, const float* __restrict__ b22,
    float* __restrict__ stats_out, u16* __restrict__ zT)
{
  // W21 dbuf [0,16384); W22 dbuf [16384,32768); tA dbuf [32768,+2*3712); tB dbuf [40192,+2*3712)
  __shared__ __align__(16) u16 lds[47616];
  const int t = threadIdx.x;
  const int lane = t & 63, wave = t >> 6;
  const int fr = lane & 15, fq = lane >> 4;
  const int n = blockIdx.x / 28;
  const int hw0 = (blockIdx.x % 28) * 112;
  const size_t nHW = (size_t)n * HW;

  // gather role: thread handles unit u=(jl,p); dummy for t>=448 (uniform load count)
  const int u = (t < 448) ? t : 447;
  const int jl = u / 112, p = u - jl * 112;
  const int pix = hw0 + p;
  const int wc = pix % 56, hc = pix / 56;

  bf16x8 gA0, gA1, gB0, gB1;
  auto gatherIssue = [&](int ks) {
    int c0 = ks * 32 + jl * 8;
    int g0 = c0 / 37;
    int s0 = 3 - g0;
    int pa0 = pix + s0;           pa0 = pa0 < 0 ? 0 : (pa0 > HW - 1 ? HW - 1 : pa0);
    int pa1 = pix + s0 - 1;       pa1 = pa1 < 0 ? 0 : (pa1 > HW - 1 ? HW - 1 : pa1);
    int pb0 = pix + 56 * s0;      pb0 = pb0 < 0 ? 0 : (pb0 > HW - 1 ? HW - 1 : pb0);
    int pb1 = pix + 56 * (s0 - 1); pb1 = pb1 < 0 ? 0 : (pb1 > HW - 1 ? HW - 1 : pb1);
    gA0 = *(const bf16x8*)(tT + (nHW + pa0) * 256 + c0);
    gA1 = *(const bf16x8*)(tT + (nHW + pa1) * 256 + c0);
    gB0 = *(const bf16x8*)(tT + (nHW + pb0) * 256 + c0);
    gB1 = *(const bf16x8*)(tT + (nHW + pb1) * 256 + c0);
  };
  auto gatherWrite = [&](int par, int ks) {
    int c0 = ks * 32 + jl * 8;
    int g0 = c0 / 37;
    int s0 = 3 - g0;
    int js = (g0 + 1) * 37 - c0; if (js > 8) js = 8;
    bool a0 = (unsigned)(wc + s0) < 56u, a1 = (unsigned)(wc + s0 - 1) < 56u;
    bool b0 = (unsigned)(hc + s0) < 56u, b1 = (unsigned)(hc + s0 - 1) < 56u;
    bf16x8 va, vb;
#pragma unroll
    for (int j = 0; j < 8; ++j) {
      bool lo = j < js;
      va[j] = lo ? (a0 ? gA0[j] : (short)0) : (a1 ? gA1[j] : (short)0);
      vb[j] = lo ? (b0 ? gB0[j] : (short)0) : (b1 ? gB1[j] : (short)0);
    }
    if (t < 448) {
      *(bf16x8*)&lds[32768 + par * 3712 + (jl * 116 + p) * 8] = va;
      *(bf16x8*)&lds[40192 + par * 3712 + (jl * 116 + p) * 8] = vb;
    }
  };
  auto stageW = [&](int par, int ks) {
    int u0 = t; int r0 = u0 >> 2, sg0 = ((u0 & 3) - (r0 >> 1)) & 3;
    int u1 = t + 512; int r1 = u1 >> 2, sg1 = ((u1 & 3) - (r1 >> 1)) & 3;
    gload16(w21 + (size_t)r0 * 256 + ks * 32 + sg0 * 8, &lds[par * 8192 + wave * 512]);
    gload16(w21 + (size_t)r1 * 256 + ks * 32 + sg1 * 8, &lds[par * 8192 + 4096 + wave * 512]);
    gload16(w22 + (size_t)r0 * 256 + ks * 32 + sg0 * 8, &lds[16384 + par * 8192 + wave * 512]);
    gload16(w22 + (size_t)r1 * 256 + ks * 32 + sg1 * 8, &lds[16384 + par * 8192 + 4096 + wave * 512]);
  };

  int aU[2], bP[7];
#pragma unroll
  for (int os = 0; os < 2; ++os) { int row = wave * 32 + os * 16 + fr; aU[os] = (4 * row + ((fq + (row >> 1)) & 3)) * 8; }
#pragma unroll
  for (int ps = 0; ps < 7; ++ps) bP[ps] = (fq * 116 + ps * 16 + fr) * 8;

  f32x4 accA[2][7], accB[2][7];
#pragma unroll
  for (int a = 0; a < 2; ++a)
#pragma unroll
    for (int b = 0; b < 7; ++b) { accA[a][b] = (f32x4){0, 0, 0, 0}; accB[a][b] = (f32x4){0, 0, 0, 0}; }

  // prologue
  gatherIssue(0);
  stageW(0, 0);
  gatherWrite(0, 0);
  gatherIssue(1);
  __syncthreads();

#pragma unroll
  for (int k = 0; k < 8; ++k) {
    if (k < 7) stageW((k + 1) & 1, k + 1);
    bf16x8 afA[2], afB[2], bfA[7], bfB[7];
#pragma unroll
    for (int os = 0; os < 2; ++os) {
      afA[os] = *(const bf16x8*)&lds[(k & 1) * 8192 + aU[os]];
      afB[os] = *(const bf16x8*)&lds[16384 + (k & 1) * 8192 + aU[os]];
    }
#pragma unroll
    for (int ps = 0; ps < 7; ++ps) {
      bfA[ps] = *(const bf16x8*)&lds[32768 + (k & 1) * 3712 + bP[ps]];
      bfB[ps] = *(const bf16x8*)&lds[40192 + (k & 1) * 3712 + bP[ps]];
    }
#pragma unroll
    for (int os = 0; os < 2; ++os)
#pragma unroll
      for (int ps = 0; ps < 7; ++ps) {
        accA[os][ps] = __builtin_amdgcn_mfma_f32_16x16x32_bf16(afA[os], bfA[ps], accA[os][ps], 0, 0, 0);
        accB[os][ps] = __builtin_amdgcn_mfma_f32_16x16x32_bf16(afB[os], bfB[ps], accB[os][ps], 0, 0, 0);
      }
    if (k < 7) {
      gatherWrite((k + 1) & 1, k + 1);
      if (k < 6) gatherIssue(k + 2);
    }
    __syncthreads();
  }

  // epilogue: z + transpose store + stats
  char* tl = (char*)lds;
  float lsum = 0.f, lsq = 0.f;
#pragma unroll
  for (int os = 0; os < 2; ++os) {
    const int ob = wave * 32 + os * 16 + fq * 4;
    float4 a4 = *(const float4*)&b21[ob];
    float4 c4 = *(const float4*)&b22[ob];
#pragma unroll
    for (int ps = 0; ps < 7; ++ps) {
      const int pixL = ps * 16 + fr;
      u16x4 pk;
      float ba[4] = {a4.x, a4.y, a4.z, a4.w};
      float bb[4] = {c4.x, c4.y, c4.z, c4.w};
#pragma unroll
      for (int j = 0; j < 4; ++j) {
        float z = fgelu(accA[os][ps][j] + ba[j]) + fgelu(accB[os][ps][j] + bb[j]);
        lsum += z; lsq += z * z;
        pk[j] = (u16)f2bf(z);
      }
      const int qd = wave * 8 + os * 4 + fq;
      const int uq = qd ^ ((pixL & 15) << 2);
      *(u16x4*)(tl + pixL * 512 + uq * 8) = pk;
    }
  }
  __syncthreads();
#pragma unroll
  for (int r = 0; r < 7; ++r) {
    int idx = t + r * 512;
    int pixL = idx >> 5, oct = idx & 31;
    int up = (2 * oct) ^ ((pixL & 15) << 2);
    bf16x8 v = *(const bf16x8*)(tl + pixL * 512 + up * 8);
    *(bf16x8*)&zT[(nHW + hw0 + pixL) * 256 + oct * 8] = v;
  }
  __syncthreads();
  float* red = (float*)lds;
  red[t] = lsum; red[512 + t] = lsq;
  __syncthreads();
  for (int off = 256; off > 0; off >>= 1) {
    if (t < off) { red[t] += red[t + off]; red[512 + t] += red[512 + t + off]; }
    __syncthreads();
  }
  if (t == 0) { atomicAdd(&stats_out[n * 2], red[0]); atomicAdd(&stats_out[n * 2 + 1], red[512]); }
}

// ---- gemm_mlp: out = x2 + fc2(fgelu(fc1(gn2(x2)))) fused; hid never leaves LDS ----
__global__ __launch_bounds__(512, 2) void gemm_mlp(
    const u16* __restrict__ x2T, const u16* __restrict__ wfc1, const u16* __restrict__ wfc2,
    const float* __restrict__ Sg, const float* __restrict__ Sb, const float* __restrict__ bias2,
    const float* __restrict__ stats_in, float* __restrict__ out_f32)
{
  // W dbuf [0,16384); B1 (x2 tile, stride 113) [16384,45312); H (stride 116) [45312,75008)
  __shared__ __align__(16) u16 lds[75008];
  const int t = threadIdx.x;
  const int lane = t & 63, wave = t >> 6;
  const int fr = lane & 15, fq = lane >> 4;
  const int n = blockIdx.x / 28;
  const int hw0 = (blockIdx.x % 28) * 112;
  const size_t nHW = (size_t)n * HW;

  auto stageWm = [&](int par, int s) {
    int chunk = s >> 4, kk = s & 7;
    int u0 = t; int r0 = u0 >> 2, sg0 = ((u0 & 3) - (r0 >> 1)) & 3;
    int u1 = t + 512; int r1 = u1 >> 2, sg1 = ((u1 & 3) - (r1 >> 1)) & 3;
    if (((s >> 3) & 1) == 0) {
      gload16(wfc1 + (size_t)(chunk * 256 + r0) * 256 + kk * 32 + sg0 * 8, &lds[par * 8192 + wave * 512]);
      gload16(wfc1 + (size_t)(chunk * 256 + r1) * 256 + kk * 32 + sg1 * 8, &lds[par * 8192 + 4096 + wave * 512]);
    } else {
      gload16(wfc2 + (size_t)r0 * 1024 + chunk * 256 + kk * 32 + sg0 * 8, &lds[par * 8192 + wave * 512]);
      gload16(wfc2 + (size_t)r1 * 1024 + chunk * 256 + kk * 32 + sg1 * 8, &lds[par * 8192 + 4096 + wave * 512]);
    }
  };

  // B1 prologue (reg-staged, padded stride 113 -> conflict-free reads)
#pragma unroll
  for (int i = 0; i < 7; ++i) {
    int u = wave * 448 + i * 64 + lane;
    int j = u / 112, p = u - j * 112;
    bf16x8 v = *(const bf16x8*)(x2T + (nHW + hw0 + p) * 256 + j * 8);
    *(bf16x8*)&lds[16384 + (j * 113 + p) * 8] = v;
  }
  stageWm(0, 0);

  float sm = stats_in[n * 2], sq = stats_in[n * 2 + 1];
  float mn = sm * (1.0f / NELF);
  float rstd = rsqrtf(sq * (1.0f / NELF) - mn * mn + EPS);
  float mr = mn * rstd;

  int aU[2];
#pragma unroll
  for (int os = 0; os < 2; ++os) { int row = wave * 32 + os * 16 + fr; aU[os] = (4 * row + ((fq + (row >> 1)) & 3)) * 8; }

  f32x4 hacc[2][7], oacc[2][7];
#pragma unroll
  for (int a = 0; a < 2; ++a)
#pragma unroll
    for (int b = 0; b < 7; ++b) { hacc[a][b] = (f32x4){0, 0, 0, 0}; oacc[a][b] = (f32x4){0, 0, 0, 0}; }

  __syncthreads();

  for (int s = 0; s < 64; ++s) {
    if (s < 63) stageWm((s + 1) & 1, s + 1);
    const int kk = s & 7;
    const bool bph = (s >> 3) & 1;
    bf16x8 afr[2], bfr[7];
#pragma unroll
    for (int os = 0; os < 2; ++os) afr[os] = *(const bf16x8*)&lds[(s & 1) * 8192 + aU[os]];
    if (!bph) {
#pragma unroll
      for (int ps = 0; ps < 7; ++ps)
        bfr[ps] = *(const bf16x8*)&lds[16384 + ((kk * 4 + fq) * 113 + ps * 16 + fr) * 8];
#pragma unroll
      for (int os = 0; os < 2; ++os)
#pragma unroll
        for (int ps = 0; ps < 7; ++ps)
          hacc[os][ps] = __builtin_amdgcn_mfma_f32_16x16x32_bf16(afr[os], bfr[ps], hacc[os][ps], 0, 0, 0);
    } else {
#pragma unroll
      for (int ps = 0; ps < 7; ++ps)
        bfr[ps] = *(const bf16x8*)&lds[45312 + ((kk * 4 + fq) * 116 + ps * 16 + fr) * 8];
#pragma unroll
      for (int os = 0; os < 2; ++os)
#pragma unroll
        for (int ps = 0; ps < 7; ++ps)
          oacc[os][ps] = __builtin_amdgcn_mfma_f32_16x16x32_bf16(afr[os], bfr[ps], oacc[os][ps], 0, 0, 0);
    }
    if ((s & 15) == 7) {
      // A-phase of chunk done: hid = fgelu(rstd*hacc + be) -> H plane, reset hacc
      const int hcb = (s >> 4) * 256;
#pragma unroll
      for (int os = 0; os < 2; ++os) {
        const int hcl = wave * 32 + os * 16 + fq * 4;
        const int hc = hcb + hcl;
        float4 g4 = *(const float4*)&Sg[hc];
        float4 s4 = *(const float4*)&Sb[hc];
        float be[4] = {s4.x - mr * g4.x, s4.y - mr * g4.y, s4.z - mr * g4.z, s4.w - mr * g4.w};
        const int jH = hcl >> 3;
#pragma unroll
        for (int ps = 0; ps < 7; ++ps) {
          const int pixL = ps * 16 + fr;
          u16x4 pk;
#pragma unroll
          for (int j = 0; j < 4; ++j)
            pk[j] = (u16)f2bf(fgelu(fmaf(hacc[os][ps][j], rstd, be[j])));
          *(u16x4*)&lds[45312 + (jH * 116 + pixL) * 8 + (fq & 1) * 4] = pk;
          hacc[os][ps] = (f32x4){0, 0, 0, 0};
        }
      }
    }
    __syncthreads();
  }

  // epilogue: out = oacc + bias + x2 (resid from B1 plane)
#pragma unroll
  for (int os = 0; os < 2; ++os) {
    const int ob = wave * 32 + os * 16 + fq * 4;
    float4 b4 = *(const float4*)&bias2[ob];
    float bb[4] = {b4.x, b4.y, b4.z, b4.w};
#pragma unroll
    for (int ps = 0; ps < 7; ++ps) {
      const int pixL = ps * 16 + fr;
      u16x4 rv = *(const u16x4*)&lds[16384 + ((ob >> 3) * 113 + pixL) * 8 + (ob & 4)];
#pragma unroll
      for (int j = 0; j < 4; ++j) {
        float v = oacc[os][ps][j] + bb[j] + b2f(rv[j]);
        out_f32[((size_t)n * 256 + ob + j) * HW + hw0 + pixL] = v;
      }
    }
  }
}

extern "C" void kernel_launch(void* const* d_in, const int* in_sizes, int n_in,
                              void* d_out, int out_size, void* d_ws, size_t ws_size,
                              hipStream_t stream) {
  const float* x     = (const float*)d_in[0];
  const float* n1_w  = (const float*)d_in[1];
  const float* n1_b  = (const float*)d_in[2];
  const float* c1_w  = (const float*)d_in[3];
  const float* c1_b  = (const float*)d_in[4];
  const float* an1_w = (const float*)d_in[5];
  const float* an1_b = (const float*)d_in[6];
  const float* c21_w = (const float*)d_in[7];
  const float* c21_b = (const float*)d_in[8];
  const float* c22_w = (const float*)d_in[9];
  const float* c22_b = (const float*)d_in[10];
  const float* an2_w = (const float*)d_in[11];
  const float* an2_b = (const float*)d_in[12];
  const float* c3_w  = (const float*)d_in[13];
  const float* c3_b  = (const float*)d_in[14];
  const float* n2_w  = (const float*)d_in[15];
  const float* n2_b  = (const float*)d_in[16];
  const float* fc1_w = (const float*)d_in[17];
  const float* fc1_b = (const float*)d_in[18];
  const float* fc2_w = (const float*)d_in[19];
  const float* fc2_b = (const float*)d_in[20];

  char* ws = (char*)d_ws;
  float* stats = (float*)ws;
  float* sums  = (float*)(ws + 1024);
  u16* wbuf = (u16*)(ws + 16384);
  u16* wb_c1g  = wbuf;
  u16* wb_c21  = wbuf + 65536;
  u16* wb_c22  = wbuf + 131072;
  u16* wb_c3g  = wbuf + 196608;
  u16* wb_fc1g = wbuf + 262144;
  u16* wb_fc2  = wbuf + 524288;
  const size_t AB = 25690112;
  char* A0 = ws + 1638400;
  u16* xT  = (u16*)(A0);
  u16* yT  = (u16*)(A0 + AB);
  u16* tT  = (u16*)(A0 + 2 * AB);
  u16* zT  = (u16*)(A0 + 3 * AB);
  u16* x2T = (u16*)(A0 + 4 * AB);
  float* out = (float*)d_out;

  hipMemsetAsync(stats, 0, 512, stream);
  wfold_kernel<<<768, 256, 0, stream>>>(c1_w, c21_w, c22_w, c3_w, fc1_w, fc2_w,
                                        n1_w, an2_w, n2_w, wbuf);
  rowsum_kernel<<<6, 256, 0, stream>>>(c1_w, c1_b, n1_w, n1_b, c3_w, c3_b, an2_w, an2_b,
                                       fc1_w, fc1_b, n2_w, n2_b, sums);
  t0_kernel<<<784, 256, 0, stream>>>(x, xT, stats + 0);
  // G1: y = conv1(gn1(x)) -> yT CL, stats(y)
  gemmW2<0><<<224, 512, 0, stream>>>(xT, wb_c1g, sums, sums + 256,
                                     stats + 0, stats + 32, nullptr, yT);
  // E2: t = fgelu(gn_as1(y)) -> tT CL
  e2_kernel<<<2048, 256, 0, stream>>>(yT, tT, an1_w, an1_b, stats + 32);
  // G2: z = fgelu(conv21(shift_w t)) + fgelu(conv22(shift_h t)) -> zT CL, stats(z)
  gemm_dual4<<<448, 512, 0, stream>>>(tT, wb_c21, wb_c22, c21_b, c22_b, stats + 64, zT);
  // G3: x2 = xT + conv3(gn_as2(z)) -> x2T CL, stats(x2)
  gemmW2<1><<<224, 512, 0, stream>>>(zT, wb_c3g, sums + 512, sums + 768,
                                     stats + 64, stats + 96, xT, x2T);
  // G4+G5 fused: out = x2 + fc2(fgelu(fc1(gn2(x2)))) -> d_out f32
  gemm_mlp<<<448, 512, 0, stream>>>(x2T, wb_fc1g, wb_fc2, sums + 1024, sums + 2048,
                                    fc2_b, stats + 96, out);
}